// Round 16
// baseline (317.190 us; speedup 1.0000x reference)
//
#include <hip/hip_runtime.h>
#include <hip/hip_bf16.h>
#include <cstdint>

// ---------------------------------------------------------------------------
// MoE CNN, hard top-1 dispatch. Round 16: conv2 -> block-per-sample (grid
// 1024) to cut weight L2 traffic 4x (1.18 GB -> 295 MB). R9's verified
// staging/pool/epilogue, but A direct from global (lane-contiguous, R10
// layout) -> zero mid-loop barriers; epilogue buffer reuses halo LDS.
// Sizes: B=1024, Cin=3, HW=32, GC=16, E=4, C1=64, C2=128, FC_IN=8192, NC=100
// Output: [final 1024*100][probs 1024*4][aux 1]
// ---------------------------------------------------------------------------

#define B_TOT 1024

typedef __attribute__((ext_vector_type(8))) short short8;
typedef __attribute__((ext_vector_type(16))) float f32x16;

__device__ __forceinline__ ushort f2bf(float f) {
  uint32_t u = __float_as_uint(f);
  u += 0x7fffu + ((u >> 16) & 1u);  // round-to-nearest-even
  return (ushort)(u >> 16);
}

// ------- K0: w2 fp32 [e][cout][ci][3][3] -> bf16 [e][kk][kb 8][cout 128][8] -
__global__ __launch_bounds__(256) void k_wprep(const float* __restrict__ w2,
                                               ushort* __restrict__ wp) {
  const int i = blockIdx.x * 256 + threadIdx.x;  // 294912 total
  const int j = i & 7;
  const int cout = (i >> 3) & 127;
  const int kb = (i >> 10) & 7;
  const int kkE = i >> 13;          // e*9 + kk
  const int kk = kkE - (kkE / 9) * 9;
  const int e = kkE / 9;
  const int ci = kb * 8 + j;
  const float f = w2[(size_t)(((e * 128 + cout) * 64 + ci) * 9) + kk];
  wp[i] = f2bf(f);
}

// ------- K0c: w1 fp32 [e][64][3][3][3] -> bf16 wA [e][kb 4][cout 64][8] ----
__global__ __launch_bounds__(256) void k_w1prep(const float* __restrict__ w1,
                                                ushort* __restrict__ wA) {
  const int i = blockIdx.x * 256 + threadIdx.x;  // 32768 total
  const int j = i & 7;
  const int cout = (i >> 3) & 63;
  const int kb = (i >> 9) & 3;
  const int e = i >> 11;
  const int k = kb * 8 + j;
  float f = 0.f;
  if (k < 27) {
    const int ci = k / 9;
    const int kk = k - ci * 9;
    f = w1[(size_t)(((e * 64 + cout) * 3 + ci) * 9) + kk];
  }
  wA[i] = f2bf(f);
}

// ---------------- K0b: efw fp32 [e][100][8192] -> bf16 [e][kb][cout128][8] -
__global__ __launch_bounds__(256) void k_wfc(const float* __restrict__ efw,
                                             ushort* __restrict__ wfc) {
  const int i = blockIdx.x * 256 + threadIdx.x;  // 4194304 total
  const int j = i & 7;
  const int cout = (i >> 3) & 127;
  const int kb = (i >> 10) & 1023;
  const int e = i >> 20;
  const int k = kb * 8 + j;
  float f = 0.f;
  if (cout < 100) f = efw[((size_t)(e * 100 + cout)) * 8192 + k];
  wfc[i] = f2bf(f);
}

// ---------------- K1: gate conv(3->16)+relu+gap, LDS halo, maskless --------
__global__ __launch_bounds__(256, 2) void k_gate(
    const float* __restrict__ x, const float* __restrict__ gcw,
    const float* __restrict__ gcb, float* __restrict__ g_mean) {
  __shared__ float xs[3 * 34 * 34];  // 13872 B zero-padded halo
  __shared__ float red[4 * 16];
  const int b = blockIdx.x;
  const int t = threadIdx.x;
  const float* xb = x + (size_t)b * 3072;

  for (int c = t; c < 3468; c += 256) {
    const int ci = c / 1156;
    const int rem = c - ci * 1156;
    const int y = rem / 34;
    const int xx = rem - y * 34;
    const int gy = y - 1, gx = xx - 1;
    float v = 0.f;
    if (gy >= 0 && gy < 32 && gx >= 0 && gx < 32) v = xb[ci * 1024 + gy * 32 + gx];
    xs[c] = v;
  }
  __syncthreads();

  const int r = t >> 3;        // output row 0..31
  const int c0 = (t & 7) * 4;  // output col base

  float accp[16][4];
#pragma unroll
  for (int c = 0; c < 16; c++)
#pragma unroll
    for (int p = 0; p < 4; p++) accp[c][p] = 0.f;

#pragma unroll
  for (int ci = 0; ci < 3; ci++) {
    float pv[3][6];
#pragma unroll
    for (int dy = 0; dy < 3; dy++) {
      const float* row = xs + ci * 1156 + (r + dy) * 34 + c0;
#pragma unroll
      for (int dx = 0; dx < 6; dx++) pv[dy][dx] = row[dx];
    }
#pragma unroll
    for (int c = 0; c < 16; c++) {
      const float* wr = gcw + (c * 3 + ci) * 9;
#pragma unroll
      for (int ky = 0; ky < 3; ky++)
#pragma unroll
        for (int kx = 0; kx < 3; kx++) {
          const float wv = wr[ky * 3 + kx];
#pragma unroll
          for (int p = 0; p < 4; p++)
            accp[c][p] += wv * pv[ky][kx + p];
        }
    }
  }

  float sums[16];
#pragma unroll
  for (int c = 0; c < 16; c++) {
    const float bb = gcb[c];
    float s = 0.f;
#pragma unroll
    for (int p = 0; p < 4; p++) s += fmaxf(accp[c][p] + bb, 0.f);
    sums[c] = s;
  }

  const int wave = t >> 6, lane = t & 63;
#pragma unroll
  for (int c = 0; c < 16; c++) {
    float v = sums[c];
    for (int o = 32; o > 0; o >>= 1) v += __shfl_down(v, o);
    if (lane == 0) red[wave * 16 + c] = v;
  }
  __syncthreads();
  if (t < 16) {
    g_mean[b * 16 + t] =
        (red[t] + red[16 + t] + red[32 + t] + red[48 + t]) * (1.f / 1024.f);
  }
}

// ---------------- K2: router linear+softmax, argmax, counts ----------------
__global__ __launch_bounds__(256) void k_router(
    const float* __restrict__ g_mean, const float* __restrict__ gfw,
    const float* __restrict__ gfb, float* __restrict__ probs,
    float* __restrict__ best_w, int* __restrict__ best_idx,
    int* __restrict__ counts) {
  const int b = blockIdx.x * 256 + threadIdx.x;
  float g[16];
#pragma unroll
  for (int c = 0; c < 16; c++) g[c] = g_mean[b * 16 + c];
  float lg[4];
#pragma unroll
  for (int e = 0; e < 4; e++) {
    float s = gfb[e];
#pragma unroll
    for (int c = 0; c < 16; c++) s += g[c] * gfw[e * 16 + c];
    lg[e] = s;
  }
  float m = fmaxf(fmaxf(lg[0], lg[1]), fmaxf(lg[2], lg[3]));
  float ex[4], s = 0.f;
#pragma unroll
  for (int e = 0; e < 4; e++) { ex[e] = expf(lg[e] - m); s += ex[e]; }
  const float inv = 1.f / s;
  float p[4];
#pragma unroll
  for (int e = 0; e < 4; e++) { p[e] = ex[e] * inv; probs[b * 4 + e] = p[e]; }
  int bi = 0; float bp = p[0];
#pragma unroll
  for (int e = 1; e < 4; e++) if (p[e] > bp) { bp = p[e]; bi = e; }
  best_w[b] = bp;
  best_idx[b] = bi;
  atomicAdd(&counts[bi], 1);
}

// ---------------- K2c: 32-aligned segment offsets --------------------------
__global__ void k_offsets(const int* __restrict__ counts, int* __restrict__ off) {
  if (threadIdx.x == 0) {
    int o = 0;
    for (int e = 0; e < 4; e++) { off[e] = o; o += ((counts[e] + 31) & ~31); }
    off[4] = o;
  }
}

// ---------------- K2d: scatter sample ids grouped by expert ----------------
__global__ __launch_bounds__(256) void k_scatter(
    const int* __restrict__ best_idx, const int* __restrict__ off,
    int* __restrict__ cnt2, int* __restrict__ order) {
  const int b = blockIdx.x * 256 + threadIdx.x;
  const int e = best_idx[b];
  const int slot = off[e] + atomicAdd(&cnt2[e], 1);
  order[slot] = b;
}

// ---------------- K3: aux loss ---------------------------------------------
__global__ __launch_bounds__(256) void k_aux(const float* __restrict__ probs,
                                             float* __restrict__ aux_out) {
  __shared__ float red[16];
  const int t = threadIdx.x;
  const int wave = t >> 6, lane = t & 63;
  float sums[4] = {0.f, 0.f, 0.f, 0.f};
  for (int b = t; b < B_TOT; b += 256) {
#pragma unroll
    for (int e = 0; e < 4; e++) sums[e] += probs[b * 4 + e];
  }
#pragma unroll
  for (int e = 0; e < 4; e++) {
    float v = sums[e];
    for (int o = 32; o > 0; o >>= 1) v += __shfl_down(v, o);
    if (lane == 0) red[wave * 4 + e] = v;
  }
  __syncthreads();
  if (t == 0) {
    float aux = 0.f;
#pragma unroll
    for (int e = 0; e < 4; e++) {
      const float mp = (red[e] + red[4 + e] + red[8 + e] + red[12 + e]) * (1.f / 1024.f);
      const float d = mp - 0.25f;
      aux += d * d;
    }
    aux_out[0] = aux * 0.25f;
  }
}

// ---------------- K4: conv1 via bf16 MFMA implicit GEMM --------------------
// Grid 4096 = sample x 4 strips. Block 256. (R15, verified)
__global__ __launch_bounds__(256) void k_conv1(
    const float* __restrict__ x, const ushort* __restrict__ wA,
    const float* __restrict__ b1, const int* __restrict__ best_idx,
    ushort* __restrict__ h1q) {
  __shared__ ushort xs[1020];                    // [ci 3][hr 10][hc 34] bf16
  __shared__ __align__(16) ushort Bl[256 * 32];  // [pos][Kpad] 16 KB
  const int blk = blockIdx.x;
  const int b = blk >> 2;
  const int q = blk & 3;  // strip: pre-pool rows 8q..8q+7
  const int t = threadIdx.x;
  const int e = __builtin_amdgcn_readfirstlane(best_idx[b]);
  const float* xb = x + (size_t)b * 3072;
  const float* b1e = b1 + (size_t)e * 64;

  for (int c = t; c < 1020; c += 256) {
    const int ci = c / 340;
    const int rem = c - ci * 340;
    const int hr = rem / 34;
    const int hc = rem - hr * 34;
    const int gr = 8 * q + hr - 1, gc = hc - 1;
    float v = 0.f;
    if (gr >= 0 && gr < 32 && gc >= 0 && gc < 32) v = xb[ci * 1024 + gr * 32 + gc];
    xs[c] = f2bf(v);
  }
  __syncthreads();

  {
    const int rr = t >> 5, cc = t & 31;
    ushort us[32];
#pragma unroll
    for (int k = 0; k < 32; k++) {
      ushort v = 0;
      if (k < 27) {
        const int ci = k / 9;
        const int tap = k - ci * 9;
        const int dy = tap / 3, dx = tap - dy * 3;
        v = xs[ci * 340 + (rr + dy) * 34 + cc + dx];
      }
      us[k] = v;
    }
    uint4 pk[2];
    uint* pu = (uint*)pk;
#pragma unroll
    for (int w = 0; w < 8; w++)
      pu[w] = (uint)us[w * 2] | ((uint)us[w * 2 + 1] << 16);
    *(uint4*)(Bl + t * 32) = pk[0];
    *(uint4*)(Bl + t * 32 + 8) = pk[1];
    uint4 pk2[2];
    uint* pu2 = (uint*)pk2;
#pragma unroll
    for (int w = 0; w < 8; w++)
      pu2[w] = (uint)us[16 + w * 2] | ((uint)us[16 + w * 2 + 1] << 16);
    *(uint4*)(Bl + t * 32 + 16) = pk2[0];
    *(uint4*)(Bl + t * 32 + 24) = pk2[1];
  }
  __syncthreads();

  const int lane = t & 63;
  const int wv = t >> 6;
  const int g = wv & 1;    // cout tile: g*32
  const int nh = wv >> 1;  // n-tiles nh*4 .. nh*4+3
  const int ln = lane & 31;
  const int half = lane >> 5;

  const short8 af0 = *(const short8*)(wA + (size_t)(((e * 4 + half) * 64) + g * 32 + ln) * 8);
  const short8 af1 = *(const short8*)(wA + (size_t)(((e * 4 + 2 + half) * 64) + g * 32 + ln) * 8);

  f32x16 acc[4];
#pragma unroll
  for (int tt = 0; tt < 4; tt++)
#pragma unroll
    for (int i = 0; i < 16; i++) acc[tt][i] = 0.f;

#pragma unroll
  for (int tt = 0; tt < 4; tt++) {
    const ushort* bcol = Bl + (size_t)((nh * 4 + tt) * 32 + ln) * 32;
    const short8 b0 = *(const short8*)(bcol + half * 8);
    const short8 b1v = *(const short8*)(bcol + 16 + half * 8);
    acc[tt] = __builtin_amdgcn_mfma_f32_32x32x16_bf16(af0, b0, acc[tt], 0, 0, 0);
    acc[tt] = __builtin_amdgcn_mfma_f32_32x32x16_bf16(af1, b1v, acc[tt], 0, 0, 0);
  }

  float bias[16];
#pragma unroll
  for (int r = 0; r < 16; r++)
    bias[r] = b1e[g * 32 + (r & 3) + 8 * (r >> 2) + 4 * half];

  const int pc = ln >> 1;
#pragma unroll
  for (int j = 0; j < 2; j++) {
    float pw[16];
#pragma unroll
    for (int r = 0; r < 16; r++) {
      float v = fmaxf(acc[2 * j][r], acc[2 * j + 1][r]);
      v = fmaxf(v, __shfl_xor(v, 1));
      pw[r] = fmaxf(v + bias[r], 0.f);
    }
    if ((lane & 1) == 0) {
      const int pos = (4 * q + nh * 2 + j) * 16 + pc;
      ushort* dst = h1q + (size_t)b * 16384 + pos * 8 + 4 * half;
#pragma unroll
      for (int rg = 0; rg < 4; rg++) {
        uint2 pk;
        pk.x = (uint)f2bf(pw[rg * 4 + 0]) | ((uint)f2bf(pw[rg * 4 + 1]) << 16);
        pk.y = (uint)f2bf(pw[rg * 4 + 2]) | ((uint)f2bf(pw[rg * 4 + 3]) << 16);
        *(uint2*)(dst + (g * 4 + rg) * 2048) = pk;
      }
    }
  }
}

// ---------------- K4b: conv2 bf16 MFMA, block-per-sample -------------------
// Grid 1024. LDS: full h1 halo [18 row][8 cig][18 col]x16B = 41.5 KB; its
// first 16 KB is reused as the bf16 epilogue buffer after the K-loop.
// Wave wv: cout group g=wv&1 (64 couts), spatial half h=wv>>1 (rows 8h..8h+7).
// Per (tap,c4): 2 lane-contiguous A global loads + 4 B ds_reads -> 8 MFMA.
__global__ __launch_bounds__(256) void k_conv2(
    const ushort* __restrict__ h1q, const ushort* __restrict__ wp,
    const float* __restrict__ b2, const int* __restrict__ best_idx,
    ushort* __restrict__ h2q) {
  __shared__ uint4 st[2592];  // [row 18][cig 8][col 18] x 16B
  const int b = blockIdx.x;
  const int t = threadIdx.x;
  const int e = __builtin_amdgcn_readfirstlane(best_idx[b]);
  const ushort* wpe = wp + (size_t)e * 73728;

  // stage full h1 halo (zero-padded)  [R9-verified]
  for (int c = t; c < 2592; c += 256) {
    const int row = c / 144;
    const int rem = c - row * 144;
    const int cig = rem / 18;
    const int col = rem - cig * 18;
    const int gy = row - 1, gx = col - 1;
    uint4 v = make_uint4(0u, 0u, 0u, 0u);
    if (gy >= 0 && gy < 16 && gx >= 0 && gx < 16)
      v = *(const uint4*)(h1q + (size_t)b * 16384 + cig * 2048 + (gy * 16 + gx) * 8);
    st[c] = v;
  }
  __syncthreads();

  const int lane = t & 63;
  const int wv = t >> 6;
  const int g = wv & 1;       // cout half: base g*64
  const int h = wv >> 1;      // spatial half: pre-pool rows 8h..8h+7
  const int half = lane >> 5; // k-half
  const int n = lane & 31;
  const int drow = n >> 4;
  const int col15 = n & 15;
  const int cm0 = g * 64;

  f32x16 acc[2][4];
#pragma unroll
  for (int m = 0; m < 2; m++)
#pragma unroll
    for (int nt = 0; nt < 4; nt++)
#pragma unroll
      for (int i = 0; i < 16; i++) acc[m][nt][i] = 0.f;

  const short* sbs = (const short*)st;

  for (int kk = 0; kk < 9; kk++) {
    const int ky = kk / 3;
    const int kx = kk - ky * 3;
#pragma unroll
    for (int c4 = 0; c4 < 4; c4++) {
      const int kb = c4 * 2 + half;
      const short8 af0 = *(const short8*)(wpe + kk * 8192 +
                                          (size_t)(kb * 128 + cm0 + n) * 8);
      const short8 af1 = *(const short8*)(wpe + kk * 8192 +
                                          (size_t)(kb * 128 + cm0 + 32 + n) * 8);
#pragma unroll
      for (int nt = 0; nt < 4; nt++) {
        const int rin = 8 * h + 2 * nt + drow + ky;
        const int cin = col15 + kx;
        const short8 bf = *(const short8*)(sbs + ((rin * 8 + kb) * 18 + cin) * 8);
        acc[0][nt] = __builtin_amdgcn_mfma_f32_32x32x16_bf16(af0, bf, acc[0][nt], 0, 0, 0);
        acc[1][nt] = __builtin_amdgcn_mfma_f32_32x32x16_bf16(af1, bf, acc[1][nt], 0, 0, 0);
      }
    }
  }
  __syncthreads();  // everyone done reading st before reuse

  // epilogue: fused 2x2 maxpool + bias + relu + bf16 into st's first 16 KB
  // [R9-verified mapping]
  ushort* pls = (ushort*)st;  // [cout 128][pos 64]
#pragma unroll
  for (int m = 0; m < 2; m++)
#pragma unroll
    for (int nt = 0; nt < 4; nt++) {
#pragma unroll
      for (int r = 0; r < 16; r++) {
        float v = acc[m][nt][r];
        v = fmaxf(v, __shfl_xor(v, 1));
        v = fmaxf(v, __shfl_xor(v, 16));
        if ((lane & 17) == 0) {  // col even, drow==0
          const int rowm = (r & 3) + 8 * (r >> 2) + 4 * half;
          const int cout = cm0 + m * 32 + rowm;
          const int pr = 4 * h + nt;
          const int pc = (n >> 1) & 7;
          pls[cout * 64 + pr * 8 + pc] = f2bf(fmaxf(v + b2[e * 128 + cout], 0.f));
        }
      }
    }
  __syncthreads();

  // coalesced full copy: pls and h2q[b] are the same flat 1024-uint4 layout
  {
    const uint4* srcv = (const uint4*)pls;
    uint4* dstv = (uint4*)(h2q + (size_t)b * 8192);
#pragma unroll
    for (int p = 0; p < 4; p++) dstv[p * 256 + t] = srcv[p * 256 + t];
  }
}

// ---------------- K5: FC bf16 MFMA, split-K=16, partial stores (no atomics) -
__global__ __launch_bounds__(256) void k_fc(
    const ushort* __restrict__ h2q, const ushort* __restrict__ wfc,
    const int* __restrict__ order, const int* __restrict__ off,
    const int* __restrict__ counts, float* __restrict__ partial) {
  __shared__ ushort bs[32 * 32 * 8];  // 16 KB
  __shared__ int sid[32];
  const int tix = blockIdx.x;
  const int ks = blockIdx.y;  // K-slice of 512
  const int base = tix * 32;
  if (base >= off[4]) return;
  int e = 0;
#pragma unroll
  for (int i = 1; i < 4; i++) if (base >= off[i]) e = i;
  const int vend = off[e] + counts[e];
  const int t = threadIdx.x;
  if (t < 32) {
    const int pos = base + t;
    sid[t] = (pos < vend) ? order[pos] : -1;
  }
  __syncthreads();

  const int lane = t & 63;
  const int wv = t >> 6;
  const int half = lane >> 5;
  const int mn = lane & 31;
  const int cout0 = wv * 32;
  const int ss = t & 31;
  const int kgrp = t >> 5;
  const int srow = sid[ss] >= 0 ? sid[ss] : 0;
  const ushort* arow = h2q + (size_t)srow * 8192;

  f32x16 acc;
#pragma unroll
  for (int i = 0; i < 16; i++) acc[i] = 0.f;

  const ushort* wbase = wfc + ((size_t)e * 1024 + (size_t)ks * 64) * 1024;
  const short* sb = (const short*)bs;

#pragma unroll
  for (int ch = 0; ch < 2; ch++) {
    const int k0g = ks * 512 + ch * 256;
    if (ch) __syncthreads();
#pragma unroll
    for (int p = 0; p < 4; p++) {
      const int kb = p * 8 + kgrp;
      const uint4 v = *(const uint4*)(arow + k0g + kb * 8);
      *(uint4*)(bs + (kb * 32 + ss) * 8) = v;
    }
    __syncthreads();
#pragma unroll
    for (int kk = 0; kk < 16; kk++) {
      const int kbl = kk * 2 + half;
      const short8 af = *(const short8*)(wbase +
          ((size_t)(ch * 32 + kbl) * 128 + cout0 + mn) * 8);
      const short8 bf = *(const short8*)(sb + (kbl * 32 + mn) * 8);
      acc = __builtin_amdgcn_mfma_f32_32x32x16_bf16(af, bf, acc, 0, 0, 0);
    }
  }

  float* pks = partial + (size_t)ks * 147456;  // 128*1152
#pragma unroll
  for (int r = 0; r < 16; r++) {
    const int cout = cout0 + (r & 3) + 8 * (r >> 2) + 4 * half;
    pks[(size_t)cout * 1152 + base + mn] = acc[r];
  }
}

// ---------------- K5b: reduce 16 K-slices, +bias, *best_w, write out ------
__global__ __launch_bounds__(256) void k_red(
    const float* __restrict__ partial, const float* __restrict__ efb,
    const int* __restrict__ order, const int* __restrict__ off,
    const int* __restrict__ counts, const float* __restrict__ best_w,
    float* __restrict__ out) {
  const int slot = blockIdx.x * 256 + threadIdx.x;
  if (slot >= off[4]) return;
  int e = 0;
#pragma unroll
  for (int i = 1; i < 4; i++) if (slot >= off[i]) e = i;
  if (slot - off[e] >= counts[e]) return;
  const int s = order[slot];
  const float bw = best_w[s];
  const int o0 = blockIdx.y * 4;
#pragma unroll
  for (int j = 0; j < 4; j++) {
    const int o = o0 + j;
    float sum = 0.f;
#pragma unroll
    for (int ks = 0; ks < 16; ks++)
      sum += partial[(size_t)ks * 147456 + (size_t)o * 1152 + slot];
    out[(size_t)s * 100 + o] = (sum + efb[e * 100 + o]) * bw;
  }
}

// ---------------------------------------------------------------------------
extern "C" void kernel_launch(void* const* d_in, const int* in_sizes, int n_in,
                              void* d_out, int out_size, void* d_ws, size_t ws_size,
                              hipStream_t stream) {
  const float* x   = (const float*)d_in[0];
  const float* gcw = (const float*)d_in[1];
  const float* gcb = (const float*)d_in[2];
  const float* gfw = (const float*)d_in[3];
  const float* gfb = (const float*)d_in[4];
  const float* c1w = (const float*)d_in[5];
  const float* c1b = (const float*)d_in[6];
  const float* c2w = (const float*)d_in[7];
  const float* c2b = (const float*)d_in[8];
  const float* efw = (const float*)d_in[9];
  const float* efb = (const float*)d_in[10];
  float* out = (float*)d_out;
  float* ws  = (float*)d_ws;

  // ws layout (float-element offsets)
  float*  g_mean   = ws;                        // 16384
  float*  best_w   = ws + 16384;                // 1024
  int*    best_idx = (int*)(ws + 17408);        // 1024
  int*    counts   = (int*)(ws + 18432);        // 4
  int*    cnt2     = (int*)(ws + 18436);        // 4
  int*    off      = (int*)(ws + 18440);        // 5
  int*    order    = (int*)(ws + 18448);        // 1152
  ushort* wp       = (ushort*)(ws + 20480);     // 294912 us  = 147456 f
  ushort* wfc      = (ushort*)(ws + 167936);    // 4194304 us = 2097152 f
  ushort* h1       = (ushort*)(ws + 2265088);   // 16777216 us = 8388608 f
  ushort* h2q      = (ushort*)(ws + 10653696);  // 8388608 us = 4194304 f -> ends 14848000
  float*  partial  = ws + 14848000;             // 2359296 f -> ends 17207296
  ushort* wA       = (ushort*)(ws + 17207296);  // 32768 us = 16384 f -> ends 17223680

  float* probs = out + 102400;
  float* aux   = out + 106496;

  hipMemsetAsync(counts, 0, 8 * sizeof(int), stream);  // counts + cnt2

  k_wprep<<<1152, 256, 0, stream>>>(c2w, wp);
  k_w1prep<<<128, 256, 0, stream>>>(c1w, wA);
  k_wfc<<<16384, 256, 0, stream>>>(efw, wfc);
  k_gate<<<1024, 256, 0, stream>>>(x, gcw, gcb, g_mean);
  k_router<<<4, 256, 0, stream>>>(g_mean, gfw, gfb, probs, best_w, best_idx, counts);
  k_offsets<<<1, 64, 0, stream>>>(counts, off);
  k_scatter<<<4, 256, 0, stream>>>(best_idx, off, cnt2, order);
  k_aux<<<1, 256, 0, stream>>>(probs, aux);
  k_conv1<<<4096, 256, 0, stream>>>(x, wA, c1b, best_idx, h1);
  k_conv2<<<1024, 256, 0, stream>>>(h1, wp, c2b, best_idx, h2q);
  dim3 g5(36, 16);
  k_fc<<<g5, 256, 0, stream>>>(h2q, wfc, order, off, counts, partial);
  dim3 g6(5, 25);
  k_red<<<g6, 256, 0, stream>>>(partial, efb, order, off, counts, best_w, out);
}

// Round 17
// 256.067 us; speedup vs baseline: 1.2387x; 1.2387x over previous
//
#include <hip/hip_runtime.h>
#include <hip/hip_bf16.h>
#include <cstdint>

// ---------------------------------------------------------------------------
// MoE CNN, hard top-1 dispatch. Round 17: conv2 grid 2048 (sample x 8-row
// strip) — midpoint of R15 (4096, 64us, L2-bound) and R16 (1024, 127us,
// occupancy-collapsed). Halves weight L2 traffic vs R15 at 23 KB LDS.
// Per (tap,c4): 2 lane-contiguous A loads + 2 B ds_reads -> 4 MFMA.
// Sizes: B=1024, Cin=3, HW=32, GC=16, E=4, C1=64, C2=128, FC_IN=8192, NC=100
// Output: [final 1024*100][probs 1024*4][aux 1]
// ---------------------------------------------------------------------------

#define B_TOT 1024

typedef __attribute__((ext_vector_type(8))) short short8;
typedef __attribute__((ext_vector_type(16))) float f32x16;

__device__ __forceinline__ ushort f2bf(float f) {
  uint32_t u = __float_as_uint(f);
  u += 0x7fffu + ((u >> 16) & 1u);  // round-to-nearest-even
  return (ushort)(u >> 16);
}

// ------- K0: w2 fp32 [e][cout][ci][3][3] -> bf16 [e][kk][kb 8][cout 128][8] -
__global__ __launch_bounds__(256) void k_wprep(const float* __restrict__ w2,
                                               ushort* __restrict__ wp) {
  const int i = blockIdx.x * 256 + threadIdx.x;  // 294912 total
  const int j = i & 7;
  const int cout = (i >> 3) & 127;
  const int kb = (i >> 10) & 7;
  const int kkE = i >> 13;          // e*9 + kk
  const int kk = kkE - (kkE / 9) * 9;
  const int e = kkE / 9;
  const int ci = kb * 8 + j;
  const float f = w2[(size_t)(((e * 128 + cout) * 64 + ci) * 9) + kk];
  wp[i] = f2bf(f);
}

// ------- K0c: w1 fp32 [e][64][3][3][3] -> bf16 wA [e][kb 4][cout 64][8] ----
__global__ __launch_bounds__(256) void k_w1prep(const float* __restrict__ w1,
                                                ushort* __restrict__ wA) {
  const int i = blockIdx.x * 256 + threadIdx.x;  // 32768 total
  const int j = i & 7;
  const int cout = (i >> 3) & 63;
  const int kb = (i >> 9) & 3;
  const int e = i >> 11;
  const int k = kb * 8 + j;
  float f = 0.f;
  if (k < 27) {
    const int ci = k / 9;
    const int kk = k - ci * 9;
    f = w1[(size_t)(((e * 64 + cout) * 3 + ci) * 9) + kk];
  }
  wA[i] = f2bf(f);
}

// ---------------- K0b: efw fp32 [e][100][8192] -> bf16 [e][kb][cout128][8] -
__global__ __launch_bounds__(256) void k_wfc(const float* __restrict__ efw,
                                             ushort* __restrict__ wfc) {
  const int i = blockIdx.x * 256 + threadIdx.x;  // 4194304 total
  const int j = i & 7;
  const int cout = (i >> 3) & 127;
  const int kb = (i >> 10) & 1023;
  const int e = i >> 20;
  const int k = kb * 8 + j;
  float f = 0.f;
  if (cout < 100) f = efw[((size_t)(e * 100 + cout)) * 8192 + k];
  wfc[i] = f2bf(f);
}

// ---------------- K1: gate conv(3->16)+relu+gap, LDS halo, maskless --------
__global__ __launch_bounds__(256, 2) void k_gate(
    const float* __restrict__ x, const float* __restrict__ gcw,
    const float* __restrict__ gcb, float* __restrict__ g_mean) {
  __shared__ float xs[3 * 34 * 34];  // 13872 B zero-padded halo
  __shared__ float red[4 * 16];
  const int b = blockIdx.x;
  const int t = threadIdx.x;
  const float* xb = x + (size_t)b * 3072;

  for (int c = t; c < 3468; c += 256) {
    const int ci = c / 1156;
    const int rem = c - ci * 1156;
    const int y = rem / 34;
    const int xx = rem - y * 34;
    const int gy = y - 1, gx = xx - 1;
    float v = 0.f;
    if (gy >= 0 && gy < 32 && gx >= 0 && gx < 32) v = xb[ci * 1024 + gy * 32 + gx];
    xs[c] = v;
  }
  __syncthreads();

  const int r = t >> 3;        // output row 0..31
  const int c0 = (t & 7) * 4;  // output col base

  float accp[16][4];
#pragma unroll
  for (int c = 0; c < 16; c++)
#pragma unroll
    for (int p = 0; p < 4; p++) accp[c][p] = 0.f;

#pragma unroll
  for (int ci = 0; ci < 3; ci++) {
    float pv[3][6];
#pragma unroll
    for (int dy = 0; dy < 3; dy++) {
      const float* row = xs + ci * 1156 + (r + dy) * 34 + c0;
#pragma unroll
      for (int dx = 0; dx < 6; dx++) pv[dy][dx] = row[dx];
    }
#pragma unroll
    for (int c = 0; c < 16; c++) {
      const float* wr = gcw + (c * 3 + ci) * 9;
#pragma unroll
      for (int ky = 0; ky < 3; ky++)
#pragma unroll
        for (int kx = 0; kx < 3; kx++) {
          const float wv = wr[ky * 3 + kx];
#pragma unroll
          for (int p = 0; p < 4; p++)
            accp[c][p] += wv * pv[ky][kx + p];
        }
    }
  }

  float sums[16];
#pragma unroll
  for (int c = 0; c < 16; c++) {
    const float bb = gcb[c];
    float s = 0.f;
#pragma unroll
    for (int p = 0; p < 4; p++) s += fmaxf(accp[c][p] + bb, 0.f);
    sums[c] = s;
  }

  const int wave = t >> 6, lane = t & 63;
#pragma unroll
  for (int c = 0; c < 16; c++) {
    float v = sums[c];
    for (int o = 32; o > 0; o >>= 1) v += __shfl_down(v, o);
    if (lane == 0) red[wave * 16 + c] = v;
  }
  __syncthreads();
  if (t < 16) {
    g_mean[b * 16 + t] =
        (red[t] + red[16 + t] + red[32 + t] + red[48 + t]) * (1.f / 1024.f);
  }
}

// ---------------- K2: router linear+softmax, argmax, counts ----------------
__global__ __launch_bounds__(256) void k_router(
    const float* __restrict__ g_mean, const float* __restrict__ gfw,
    const float* __restrict__ gfb, float* __restrict__ probs,
    float* __restrict__ best_w, int* __restrict__ best_idx,
    int* __restrict__ counts) {
  const int b = blockIdx.x * 256 + threadIdx.x;
  float g[16];
#pragma unroll
  for (int c = 0; c < 16; c++) g[c] = g_mean[b * 16 + c];
  float lg[4];
#pragma unroll
  for (int e = 0; e < 4; e++) {
    float s = gfb[e];
#pragma unroll
    for (int c = 0; c < 16; c++) s += g[c] * gfw[e * 16 + c];
    lg[e] = s;
  }
  float m = fmaxf(fmaxf(lg[0], lg[1]), fmaxf(lg[2], lg[3]));
  float ex[4], s = 0.f;
#pragma unroll
  for (int e = 0; e < 4; e++) { ex[e] = expf(lg[e] - m); s += ex[e]; }
  const float inv = 1.f / s;
  float p[4];
#pragma unroll
  for (int e = 0; e < 4; e++) { p[e] = ex[e] * inv; probs[b * 4 + e] = p[e]; }
  int bi = 0; float bp = p[0];
#pragma unroll
  for (int e = 1; e < 4; e++) if (p[e] > bp) { bp = p[e]; bi = e; }
  best_w[b] = bp;
  best_idx[b] = bi;
  atomicAdd(&counts[bi], 1);
}

// ---------------- K2c: 32-aligned segment offsets --------------------------
__global__ void k_offsets(const int* __restrict__ counts, int* __restrict__ off) {
  if (threadIdx.x == 0) {
    int o = 0;
    for (int e = 0; e < 4; e++) { off[e] = o; o += ((counts[e] + 31) & ~31); }
    off[4] = o;
  }
}

// ---------------- K2d: scatter sample ids grouped by expert ----------------
__global__ __launch_bounds__(256) void k_scatter(
    const int* __restrict__ best_idx, const int* __restrict__ off,
    int* __restrict__ cnt2, int* __restrict__ order) {
  const int b = blockIdx.x * 256 + threadIdx.x;
  const int e = best_idx[b];
  const int slot = off[e] + atomicAdd(&cnt2[e], 1);
  order[slot] = b;
}

// ---------------- K3: aux loss ---------------------------------------------
__global__ __launch_bounds__(256) void k_aux(const float* __restrict__ probs,
                                             float* __restrict__ aux_out) {
  __shared__ float red[16];
  const int t = threadIdx.x;
  const int wave = t >> 6, lane = t & 63;
  float sums[4] = {0.f, 0.f, 0.f, 0.f};
  for (int b = t; b < B_TOT; b += 256) {
#pragma unroll
    for (int e = 0; e < 4; e++) sums[e] += probs[b * 4 + e];
  }
#pragma unroll
  for (int e = 0; e < 4; e++) {
    float v = sums[e];
    for (int o = 32; o > 0; o >>= 1) v += __shfl_down(v, o);
    if (lane == 0) red[wave * 4 + e] = v;
  }
  __syncthreads();
  if (t == 0) {
    float aux = 0.f;
#pragma unroll
    for (int e = 0; e < 4; e++) {
      const float mp = (red[e] + red[4 + e] + red[8 + e] + red[12 + e]) * (1.f / 1024.f);
      const float d = mp - 0.25f;
      aux += d * d;
    }
    aux_out[0] = aux * 0.25f;
  }
}

// ---------------- K4: conv1 via bf16 MFMA implicit GEMM (R15, verified) ----
__global__ __launch_bounds__(256) void k_conv1(
    const float* __restrict__ x, const ushort* __restrict__ wA,
    const float* __restrict__ b1, const int* __restrict__ best_idx,
    ushort* __restrict__ h1q) {
  __shared__ ushort xs[1020];                    // [ci 3][hr 10][hc 34] bf16
  __shared__ __align__(16) ushort Bl[256 * 32];  // [pos][Kpad] 16 KB
  const int blk = blockIdx.x;
  const int b = blk >> 2;
  const int q = blk & 3;  // strip: pre-pool rows 8q..8q+7
  const int t = threadIdx.x;
  const int e = __builtin_amdgcn_readfirstlane(best_idx[b]);
  const float* xb = x + (size_t)b * 3072;
  const float* b1e = b1 + (size_t)e * 64;

  for (int c = t; c < 1020; c += 256) {
    const int ci = c / 340;
    const int rem = c - ci * 340;
    const int hr = rem / 34;
    const int hc = rem - hr * 34;
    const int gr = 8 * q + hr - 1, gc = hc - 1;
    float v = 0.f;
    if (gr >= 0 && gr < 32 && gc >= 0 && gc < 32) v = xb[ci * 1024 + gr * 32 + gc];
    xs[c] = f2bf(v);
  }
  __syncthreads();

  {
    const int rr = t >> 5, cc = t & 31;
    ushort us[32];
#pragma unroll
    for (int k = 0; k < 32; k++) {
      ushort v = 0;
      if (k < 27) {
        const int ci = k / 9;
        const int tap = k - ci * 9;
        const int dy = tap / 3, dx = tap - dy * 3;
        v = xs[ci * 340 + (rr + dy) * 34 + cc + dx];
      }
      us[k] = v;
    }
    uint4 pk[2];
    uint* pu = (uint*)pk;
#pragma unroll
    for (int w = 0; w < 8; w++)
      pu[w] = (uint)us[w * 2] | ((uint)us[w * 2 + 1] << 16);
    *(uint4*)(Bl + t * 32) = pk[0];
    *(uint4*)(Bl + t * 32 + 8) = pk[1];
    uint4 pk2[2];
    uint* pu2 = (uint*)pk2;
#pragma unroll
    for (int w = 0; w < 8; w++)
      pu2[w] = (uint)us[16 + w * 2] | ((uint)us[16 + w * 2 + 1] << 16);
    *(uint4*)(Bl + t * 32 + 16) = pk2[0];
    *(uint4*)(Bl + t * 32 + 24) = pk2[1];
  }
  __syncthreads();

  const int lane = t & 63;
  const int wv = t >> 6;
  const int g = wv & 1;    // cout tile: g*32
  const int nh = wv >> 1;  // n-tiles nh*4 .. nh*4+3
  const int ln = lane & 31;
  const int half = lane >> 5;

  const short8 af0 = *(const short8*)(wA + (size_t)(((e * 4 + half) * 64) + g * 32 + ln) * 8);
  const short8 af1 = *(const short8*)(wA + (size_t)(((e * 4 + 2 + half) * 64) + g * 32 + ln) * 8);

  f32x16 acc[4];
#pragma unroll
  for (int tt = 0; tt < 4; tt++)
#pragma unroll
    for (int i = 0; i < 16; i++) acc[tt][i] = 0.f;

#pragma unroll
  for (int tt = 0; tt < 4; tt++) {
    const ushort* bcol = Bl + (size_t)((nh * 4 + tt) * 32 + ln) * 32;
    const short8 b0 = *(const short8*)(bcol + half * 8);
    const short8 b1v = *(const short8*)(bcol + 16 + half * 8);
    acc[tt] = __builtin_amdgcn_mfma_f32_32x32x16_bf16(af0, b0, acc[tt], 0, 0, 0);
    acc[tt] = __builtin_amdgcn_mfma_f32_32x32x16_bf16(af1, b1v, acc[tt], 0, 0, 0);
  }

  float bias[16];
#pragma unroll
  for (int r = 0; r < 16; r++)
    bias[r] = b1e[g * 32 + (r & 3) + 8 * (r >> 2) + 4 * half];

  const int pc = ln >> 1;
#pragma unroll
  for (int j = 0; j < 2; j++) {
    float pw[16];
#pragma unroll
    for (int r = 0; r < 16; r++) {
      float v = fmaxf(acc[2 * j][r], acc[2 * j + 1][r]);
      v = fmaxf(v, __shfl_xor(v, 1));
      pw[r] = fmaxf(v + bias[r], 0.f);
    }
    if ((lane & 1) == 0) {
      const int pos = (4 * q + nh * 2 + j) * 16 + pc;
      ushort* dst = h1q + (size_t)b * 16384 + pos * 8 + 4 * half;
#pragma unroll
      for (int rg = 0; rg < 4; rg++) {
        uint2 pk;
        pk.x = (uint)f2bf(pw[rg * 4 + 0]) | ((uint)f2bf(pw[rg * 4 + 1]) << 16);
        pk.y = (uint)f2bf(pw[rg * 4 + 2]) | ((uint)f2bf(pw[rg * 4 + 3]) << 16);
        *(uint2*)(dst + (g * 4 + rg) * 2048) = pk;
      }
    }
  }
}

// ---------------- K4b: conv2 bf16 MFMA, grid 2048 (8-row strips) -----------
// LDS: halo [row 10][cig 8][col 18]x16B = 22.5 KB, reused for epilogue.
// Wave wv: cout group g=wv&1 (64), row-quad h=wv>>1 (strip rows 4h..4h+3).
// Per (tap,c4): 2 lane-contiguous A loads + 2 B ds_reads -> 4 MFMA.
__global__ __launch_bounds__(256) void k_conv2(
    const ushort* __restrict__ h1q, const ushort* __restrict__ wp,
    const float* __restrict__ b2, const int* __restrict__ best_idx,
    ushort* __restrict__ h2q) {
  __shared__ uint4 st[1440];  // [row 10][cig 8][col 18] x 16B
  const int blk = blockIdx.x;
  const int b = blk >> 1;
  const int q = blk & 1;  // out rows 8q..8q+7
  const int t = threadIdx.x;
  const int e = __builtin_amdgcn_readfirstlane(best_idx[b]);
  const ushort* wpe = wp + (size_t)e * 73728;

  // stage halo rows 8q-1 .. 8q+8 (zero-padded)
  for (int c = t; c < 1440; c += 256) {
    const int row = c / 144;
    const int rem = c - row * 144;
    const int cig = rem / 18;
    const int col = rem - cig * 18;
    const int gy = 8 * q - 1 + row, gx = col - 1;
    uint4 v = make_uint4(0u, 0u, 0u, 0u);
    if (gy >= 0 && gy < 16 && gx >= 0 && gx < 16)
      v = *(const uint4*)(h1q + (size_t)b * 16384 + cig * 2048 + (gy * 16 + gx) * 8);
    st[c] = v;  // index (row*8+cig)*18+col
  }
  __syncthreads();

  const int lane = t & 63;
  const int wv = t >> 6;
  const int g = wv & 1;       // cout half: base g*64
  const int h = wv >> 1;      // strip row-quad: local rows 4h..4h+3
  const int half = lane >> 5; // k-half
  const int n = lane & 31;
  const int drow = n >> 4;
  const int col15 = n & 15;
  const int cm0 = g * 64;

  f32x16 acc[2][2];  // [m: cout tile][nt: row pair]
#pragma unroll
  for (int m = 0; m < 2; m++)
#pragma unroll
    for (int nt = 0; nt < 2; nt++)
#pragma unroll
      for (int i = 0; i < 16; i++) acc[m][nt][i] = 0.f;

  const short* sbs = (const short*)st;

  for (int kk = 0; kk < 9; kk++) {
    const int ky = kk / 3;
    const int kx = kk - ky * 3;
#pragma unroll
    for (int c4 = 0; c4 < 4; c4++) {
      const int kb = c4 * 2 + half;
      const short8 af0 = *(const short8*)(wpe + kk * 8192 +
                                          (size_t)(kb * 128 + cm0 + n) * 8);
      const short8 af1 = *(const short8*)(wpe + kk * 8192 +
                                          (size_t)(kb * 128 + cm0 + 32 + n) * 8);
#pragma unroll
      for (int nt = 0; nt < 2; nt++) {
        const int rin = 4 * h + 2 * nt + drow + ky;  // halo row 0..9
        const int cin = col15 + kx;                  // halo col 0..17
        const short8 bf = *(const short8*)(sbs + ((rin * 8 + kb) * 18 + cin) * 8);
        acc[0][nt] = __builtin_amdgcn_mfma_f32_32x32x16_bf16(af0, bf, acc[0][nt], 0, 0, 0);
        acc[1][nt] = __builtin_amdgcn_mfma_f32_32x32x16_bf16(af1, bf, acc[1][nt], 0, 0, 0);
      }
    }
  }
  __syncthreads();  // done reading halo before LDS reuse

  // epilogue: fused 2x2 maxpool + bias + relu + bf16 into st's first 8 KB
  // pls layout: [cout 128][prl 4][pc 8]  (prl = 2h+nt, abs pooled row 4q+prl)
  ushort* pls = (ushort*)st;
#pragma unroll
  for (int m = 0; m < 2; m++)
#pragma unroll
    for (int nt = 0; nt < 2; nt++) {
#pragma unroll
      for (int r = 0; r < 16; r++) {
        float v = acc[m][nt][r];
        v = fmaxf(v, __shfl_xor(v, 1));
        v = fmaxf(v, __shfl_xor(v, 16));
        if ((lane & 17) == 0) {  // col even, drow==0
          const int rowm = (r & 3) + 8 * (r >> 2) + 4 * half;
          const int cout = cm0 + m * 32 + rowm;
          const int prl = 2 * h + nt;
          const int pc = (n >> 1) & 7;
          pls[cout * 32 + prl * 8 + pc] = f2bf(fmaxf(v + b2[e * 128 + cout], 0.f));
        }
      }
    }
  __syncthreads();

  // coalesced copy: 512 uint4; dst = h2q[b][cout][4q+prl][pc]
  {
#pragma unroll
    for (int p = 0; p < 2; p++) {
      const int f16 = p * 256 + t;      // uint4 index
      const int flat = f16 * 8;         // ushort index: cout*32 + pos32
      const int cout = flat >> 5;
      const int pos32 = flat & 31;
      uint4* dst = (uint4*)(h2q + (size_t)b * 8192 + cout * 64 + 32 * q + pos32);
      *dst = ((const uint4*)pls)[f16];
    }
  }
}

// ---------------- K5: FC bf16 MFMA, split-K=16, partial stores (no atomics) -
__global__ __launch_bounds__(256) void k_fc(
    const ushort* __restrict__ h2q, const ushort* __restrict__ wfc,
    const int* __restrict__ order, const int* __restrict__ off,
    const int* __restrict__ counts, float* __restrict__ partial) {
  __shared__ ushort bs[32 * 32 * 8];  // 16 KB
  __shared__ int sid[32];
  const int tix = blockIdx.x;
  const int ks = blockIdx.y;  // K-slice of 512
  const int base = tix * 32;
  if (base >= off[4]) return;
  int e = 0;
#pragma unroll
  for (int i = 1; i < 4; i++) if (base >= off[i]) e = i;
  const int vend = off[e] + counts[e];
  const int t = threadIdx.x;
  if (t < 32) {
    const int pos = base + t;
    sid[t] = (pos < vend) ? order[pos] : -1;
  }
  __syncthreads();

  const int lane = t & 63;
  const int wv = t >> 6;
  const int half = lane >> 5;
  const int mn = lane & 31;
  const int cout0 = wv * 32;
  const int ss = t & 31;
  const int kgrp = t >> 5;
  const int srow = sid[ss] >= 0 ? sid[ss] : 0;
  const ushort* arow = h2q + (size_t)srow * 8192;

  f32x16 acc;
#pragma unroll
  for (int i = 0; i < 16; i++) acc[i] = 0.f;

  const ushort* wbase = wfc + ((size_t)e * 1024 + (size_t)ks * 64) * 1024;
  const short* sb = (const short*)bs;

#pragma unroll
  for (int ch = 0; ch < 2; ch++) {
    const int k0g = ks * 512 + ch * 256;
    if (ch) __syncthreads();
#pragma unroll
    for (int p = 0; p < 4; p++) {
      const int kb = p * 8 + kgrp;
      const uint4 v = *(const uint4*)(arow + k0g + kb * 8);
      *(uint4*)(bs + (kb * 32 + ss) * 8) = v;
    }
    __syncthreads();
#pragma unroll
    for (int kk = 0; kk < 16; kk++) {
      const int kbl = kk * 2 + half;
      const short8 af = *(const short8*)(wbase +
          ((size_t)(ch * 32 + kbl) * 128 + cout0 + mn) * 8);
      const short8 bf = *(const short8*)(sb + (kbl * 32 + mn) * 8);
      acc = __builtin_amdgcn_mfma_f32_32x32x16_bf16(af, bf, acc, 0, 0, 0);
    }
  }

  float* pks = partial + (size_t)ks * 147456;  // 128*1152
#pragma unroll
  for (int r = 0; r < 16; r++) {
    const int cout = cout0 + (r & 3) + 8 * (r >> 2) + 4 * half;
    pks[(size_t)cout * 1152 + base + mn] = acc[r];
  }
}

// ---------------- K5b: reduce 16 K-slices, +bias, *best_w, write out ------
__global__ __launch_bounds__(256) void k_red(
    const float* __restrict__ partial, const float* __restrict__ efb,
    const int* __restrict__ order, const int* __restrict__ off,
    const int* __restrict__ counts, const float* __restrict__ best_w,
    float* __restrict__ out) {
  const int slot = blockIdx.x * 256 + threadIdx.x;
  if (slot >= off[4]) return;
  int e = 0;
#pragma unroll
  for (int i = 1; i < 4; i++) if (slot >= off[i]) e = i;
  if (slot - off[e] >= counts[e]) return;
  const int s = order[slot];
  const float bw = best_w[s];
  const int o0 = blockIdx.y * 4;
#pragma unroll
  for (int j = 0; j < 4; j++) {
    const int o = o0 + j;
    float sum = 0.f;
#pragma unroll
    for (int ks = 0; ks < 16; ks++)
      sum += partial[(size_t)ks * 147456 + (size_t)o * 1152 + slot];
    out[(size_t)s * 100 + o] = (sum + efb[e * 100 + o]) * bw;
  }
}

// ---------------------------------------------------------------------------
extern "C" void kernel_launch(void* const* d_in, const int* in_sizes, int n_in,
                              void* d_out, int out_size, void* d_ws, size_t ws_size,
                              hipStream_t stream) {
  const float* x   = (const float*)d_in[0];
  const float* gcw = (const float*)d_in[1];
  const float* gcb = (const float*)d_in[2];
  const float* gfw = (const float*)d_in[3];
  const float* gfb = (const float*)d_in[4];
  const float* c1w = (const float*)d_in[5];
  const float* c1b = (const float*)d_in[6];
  const float* c2w = (const float*)d_in[7];
  const float* c2b = (const float*)d_in[8];
  const float* efw = (const float*)d_in[9];
  const float* efb = (const float*)d_in[10];
  float* out = (float*)d_out;
  float* ws  = (float*)d_ws;

  // ws layout (float-element offsets)
  float*  g_mean   = ws;                        // 16384
  float*  best_w   = ws + 16384;                // 1024
  int*    best_idx = (int*)(ws + 17408);        // 1024
  int*    counts   = (int*)(ws + 18432);        // 4
  int*    cnt2     = (int*)(ws + 18436);        // 4
  int*    off      = (int*)(ws + 18440);        // 5
  int*    order    = (int*)(ws + 18448);        // 1152
  ushort* wp       = (ushort*)(ws + 20480);     // 294912 us  = 147456 f
  ushort* wfc      = (ushort*)(ws + 167936);    // 4194304 us = 2097152 f
  ushort* h1       = (ushort*)(ws + 2265088);   // 16777216 us = 8388608 f
  ushort* h2q      = (ushort*)(ws + 10653696);  // 8388608 us = 4194304 f -> ends 14848000
  float*  partial  = ws + 14848000;             // 2359296 f -> ends 17207296
  ushort* wA       = (ushort*)(ws + 17207296);  // 32768 us = 16384 f -> ends 17223680

  float* probs = out + 102400;
  float* aux   = out + 106496;

  hipMemsetAsync(counts, 0, 8 * sizeof(int), stream);  // counts + cnt2

  k_wprep<<<1152, 256, 0, stream>>>(c2w, wp);
  k_w1prep<<<128, 256, 0, stream>>>(c1w, wA);
  k_wfc<<<16384, 256, 0, stream>>>(efw, wfc);
  k_gate<<<1024, 256, 0, stream>>>(x, gcw, gcb, g_mean);
  k_router<<<4, 256, 0, stream>>>(g_mean, gfw, gfb, probs, best_w, best_idx, counts);
  k_offsets<<<1, 64, 0, stream>>>(counts, off);
  k_scatter<<<4, 256, 0, stream>>>(best_idx, off, cnt2, order);
  k_aux<<<1, 256, 0, stream>>>(probs, aux);
  k_conv1<<<4096, 256, 0, stream>>>(x, wA, c1b, best_idx, h1);
  k_conv2<<<2048, 256, 0, stream>>>(h1, wp, c2b, best_idx, h2q);
  dim3 g5(36, 16);
  k_fc<<<g5, 256, 0, stream>>>(h2q, wfc, order, off, counts, partial);
  dim3 g6(5, 25);
  k_red<<<g6, 256, 0, stream>>>(partial, efb, order, off, counts, best_w, out);
}

// Round 18
// 248.658 us; speedup vs baseline: 1.2756x; 1.0298x over previous
//
#include <hip/hip_runtime.h>
#include <hip/hip_bf16.h>
#include <cstdint>

// ---------------------------------------------------------------------------
// MoE CNN, hard top-1 dispatch. Round 18: conv2 = R15 structure (grid 4096,
// best measured) + software-pipelined A loads: in-place register rotation,
// load tap kk+1 right after tap kk's MFMAs consume the regs (AITER-style
// MFMA<->load interleave, partial vmcnt waits). One variable vs R15.
// Sizes: B=1024, Cin=3, HW=32, GC=16, E=4, C1=64, C2=128, FC_IN=8192, NC=100
// Output: [final 1024*100][probs 1024*4][aux 1]
// ---------------------------------------------------------------------------

#define B_TOT 1024

typedef __attribute__((ext_vector_type(8))) short short8;
typedef __attribute__((ext_vector_type(16))) float f32x16;

__device__ __forceinline__ ushort f2bf(float f) {
  uint32_t u = __float_as_uint(f);
  u += 0x7fffu + ((u >> 16) & 1u);  // round-to-nearest-even
  return (ushort)(u >> 16);
}

// ------- K0: w2 fp32 [e][cout][ci][3][3] -> bf16 [e][kk][kb 8][cout 128][8] -
__global__ __launch_bounds__(256) void k_wprep(const float* __restrict__ w2,
                                               ushort* __restrict__ wp) {
  const int i = blockIdx.x * 256 + threadIdx.x;  // 294912 total
  const int j = i & 7;
  const int cout = (i >> 3) & 127;
  const int kb = (i >> 10) & 7;
  const int kkE = i >> 13;          // e*9 + kk
  const int kk = kkE - (kkE / 9) * 9;
  const int e = kkE / 9;
  const int ci = kb * 8 + j;
  const float f = w2[(size_t)(((e * 128 + cout) * 64 + ci) * 9) + kk];
  wp[i] = f2bf(f);
}

// ------- K0c: w1 fp32 [e][64][3][3][3] -> bf16 wA [e][kb 4][cout 64][8] ----
__global__ __launch_bounds__(256) void k_w1prep(const float* __restrict__ w1,
                                                ushort* __restrict__ wA) {
  const int i = blockIdx.x * 256 + threadIdx.x;  // 32768 total
  const int j = i & 7;
  const int cout = (i >> 3) & 63;
  const int kb = (i >> 9) & 3;
  const int e = i >> 11;
  const int k = kb * 8 + j;
  float f = 0.f;
  if (k < 27) {
    const int ci = k / 9;
    const int kk = k - ci * 9;
    f = w1[(size_t)(((e * 64 + cout) * 3 + ci) * 9) + kk];
  }
  wA[i] = f2bf(f);
}

// ---------------- K0b: efw fp32 [e][100][8192] -> bf16 [e][kb][cout128][8] -
__global__ __launch_bounds__(256) void k_wfc(const float* __restrict__ efw,
                                             ushort* __restrict__ wfc) {
  const int i = blockIdx.x * 256 + threadIdx.x;  // 4194304 total
  const int j = i & 7;
  const int cout = (i >> 3) & 127;
  const int kb = (i >> 10) & 1023;
  const int e = i >> 20;
  const int k = kb * 8 + j;
  float f = 0.f;
  if (cout < 100) f = efw[((size_t)(e * 100 + cout)) * 8192 + k];
  wfc[i] = f2bf(f);
}

// ---------------- K1: gate conv(3->16)+relu+gap, LDS halo, maskless --------
__global__ __launch_bounds__(256, 2) void k_gate(
    const float* __restrict__ x, const float* __restrict__ gcw,
    const float* __restrict__ gcb, float* __restrict__ g_mean) {
  __shared__ float xs[3 * 34 * 34];  // 13872 B zero-padded halo
  __shared__ float red[4 * 16];
  const int b = blockIdx.x;
  const int t = threadIdx.x;
  const float* xb = x + (size_t)b * 3072;

  for (int c = t; c < 3468; c += 256) {
    const int ci = c / 1156;
    const int rem = c - ci * 1156;
    const int y = rem / 34;
    const int xx = rem - y * 34;
    const int gy = y - 1, gx = xx - 1;
    float v = 0.f;
    if (gy >= 0 && gy < 32 && gx >= 0 && gx < 32) v = xb[ci * 1024 + gy * 32 + gx];
    xs[c] = v;
  }
  __syncthreads();

  const int r = t >> 3;        // output row 0..31
  const int c0 = (t & 7) * 4;  // output col base

  float accp[16][4];
#pragma unroll
  for (int c = 0; c < 16; c++)
#pragma unroll
    for (int p = 0; p < 4; p++) accp[c][p] = 0.f;

#pragma unroll
  for (int ci = 0; ci < 3; ci++) {
    float pv[3][6];
#pragma unroll
    for (int dy = 0; dy < 3; dy++) {
      const float* row = xs + ci * 1156 + (r + dy) * 34 + c0;
#pragma unroll
      for (int dx = 0; dx < 6; dx++) pv[dy][dx] = row[dx];
    }
#pragma unroll
    for (int c = 0; c < 16; c++) {
      const float* wr = gcw + (c * 3 + ci) * 9;
#pragma unroll
      for (int ky = 0; ky < 3; ky++)
#pragma unroll
        for (int kx = 0; kx < 3; kx++) {
          const float wv = wr[ky * 3 + kx];
#pragma unroll
          for (int p = 0; p < 4; p++)
            accp[c][p] += wv * pv[ky][kx + p];
        }
    }
  }

  float sums[16];
#pragma unroll
  for (int c = 0; c < 16; c++) {
    const float bb = gcb[c];
    float s = 0.f;
#pragma unroll
    for (int p = 0; p < 4; p++) s += fmaxf(accp[c][p] + bb, 0.f);
    sums[c] = s;
  }

  const int wave = t >> 6, lane = t & 63;
#pragma unroll
  for (int c = 0; c < 16; c++) {
    float v = sums[c];
    for (int o = 32; o > 0; o >>= 1) v += __shfl_down(v, o);
    if (lane == 0) red[wave * 16 + c] = v;
  }
  __syncthreads();
  if (t < 16) {
    g_mean[b * 16 + t] =
        (red[t] + red[16 + t] + red[32 + t] + red[48 + t]) * (1.f / 1024.f);
  }
}

// ---------------- K2: router linear+softmax, argmax, counts ----------------
__global__ __launch_bounds__(256) void k_router(
    const float* __restrict__ g_mean, const float* __restrict__ gfw,
    const float* __restrict__ gfb, float* __restrict__ probs,
    float* __restrict__ best_w, int* __restrict__ best_idx,
    int* __restrict__ counts) {
  const int b = blockIdx.x * 256 + threadIdx.x;
  float g[16];
#pragma unroll
  for (int c = 0; c < 16; c++) g[c] = g_mean[b * 16 + c];
  float lg[4];
#pragma unroll
  for (int e = 0; e < 4; e++) {
    float s = gfb[e];
#pragma unroll
    for (int c = 0; c < 16; c++) s += g[c] * gfw[e * 16 + c];
    lg[e] = s;
  }
  float m = fmaxf(fmaxf(lg[0], lg[1]), fmaxf(lg[2], lg[3]));
  float ex[4], s = 0.f;
#pragma unroll
  for (int e = 0; e < 4; e++) { ex[e] = expf(lg[e] - m); s += ex[e]; }
  const float inv = 1.f / s;
  float p[4];
#pragma unroll
  for (int e = 0; e < 4; e++) { p[e] = ex[e] * inv; probs[b * 4 + e] = p[e]; }
  int bi = 0; float bp = p[0];
#pragma unroll
  for (int e = 1; e < 4; e++) if (p[e] > bp) { bp = p[e]; bi = e; }
  best_w[b] = bp;
  best_idx[b] = bi;
  atomicAdd(&counts[bi], 1);
}

// ---------------- K2c: 32-aligned segment offsets --------------------------
__global__ void k_offsets(const int* __restrict__ counts, int* __restrict__ off) {
  if (threadIdx.x == 0) {
    int o = 0;
    for (int e = 0; e < 4; e++) { off[e] = o; o += ((counts[e] + 31) & ~31); }
    off[4] = o;
  }
}

// ---------------- K2d: scatter sample ids grouped by expert ----------------
__global__ __launch_bounds__(256) void k_scatter(
    const int* __restrict__ best_idx, const int* __restrict__ off,
    int* __restrict__ cnt2, int* __restrict__ order) {
  const int b = blockIdx.x * 256 + threadIdx.x;
  const int e = best_idx[b];
  const int slot = off[e] + atomicAdd(&cnt2[e], 1);
  order[slot] = b;
}

// ---------------- K3: aux loss ---------------------------------------------
__global__ __launch_bounds__(256) void k_aux(const float* __restrict__ probs,
                                             float* __restrict__ aux_out) {
  __shared__ float red[16];
  const int t = threadIdx.x;
  const int wave = t >> 6, lane = t & 63;
  float sums[4] = {0.f, 0.f, 0.f, 0.f};
  for (int b = t; b < B_TOT; b += 256) {
#pragma unroll
    for (int e = 0; e < 4; e++) sums[e] += probs[b * 4 + e];
  }
#pragma unroll
  for (int e = 0; e < 4; e++) {
    float v = sums[e];
    for (int o = 32; o > 0; o >>= 1) v += __shfl_down(v, o);
    if (lane == 0) red[wave * 4 + e] = v;
  }
  __syncthreads();
  if (t == 0) {
    float aux = 0.f;
#pragma unroll
    for (int e = 0; e < 4; e++) {
      const float mp = (red[e] + red[4 + e] + red[8 + e] + red[12 + e]) * (1.f / 1024.f);
      const float d = mp - 0.25f;
      aux += d * d;
    }
    aux_out[0] = aux * 0.25f;
  }
}

// ---------------- K4: conv1 via bf16 MFMA implicit GEMM (R15, verified) ----
__global__ __launch_bounds__(256) void k_conv1(
    const float* __restrict__ x, const ushort* __restrict__ wA,
    const float* __restrict__ b1, const int* __restrict__ best_idx,
    ushort* __restrict__ h1q) {
  __shared__ ushort xs[1020];                    // [ci 3][hr 10][hc 34] bf16
  __shared__ __align__(16) ushort Bl[256 * 32];  // [pos][Kpad] 16 KB
  const int blk = blockIdx.x;
  const int b = blk >> 2;
  const int q = blk & 3;  // strip: pre-pool rows 8q..8q+7
  const int t = threadIdx.x;
  const int e = __builtin_amdgcn_readfirstlane(best_idx[b]);
  const float* xb = x + (size_t)b * 3072;
  const float* b1e = b1 + (size_t)e * 64;

  for (int c = t; c < 1020; c += 256) {
    const int ci = c / 340;
    const int rem = c - ci * 340;
    const int hr = rem / 34;
    const int hc = rem - hr * 34;
    const int gr = 8 * q + hr - 1, gc = hc - 1;
    float v = 0.f;
    if (gr >= 0 && gr < 32 && gc >= 0 && gc < 32) v = xb[ci * 1024 + gr * 32 + gc];
    xs[c] = f2bf(v);
  }
  __syncthreads();

  {
    const int rr = t >> 5, cc = t & 31;
    ushort us[32];
#pragma unroll
    for (int k = 0; k < 32; k++) {
      ushort v = 0;
      if (k < 27) {
        const int ci = k / 9;
        const int tap = k - ci * 9;
        const int dy = tap / 3, dx = tap - dy * 3;
        v = xs[ci * 340 + (rr + dy) * 34 + cc + dx];
      }
      us[k] = v;
    }
    uint4 pk[2];
    uint* pu = (uint*)pk;
#pragma unroll
    for (int w = 0; w < 8; w++)
      pu[w] = (uint)us[w * 2] | ((uint)us[w * 2 + 1] << 16);
    *(uint4*)(Bl + t * 32) = pk[0];
    *(uint4*)(Bl + t * 32 + 8) = pk[1];
    uint4 pk2[2];
    uint* pu2 = (uint*)pk2;
#pragma unroll
    for (int w = 0; w < 8; w++)
      pu2[w] = (uint)us[16 + w * 2] | ((uint)us[16 + w * 2 + 1] << 16);
    *(uint4*)(Bl + t * 32 + 16) = pk2[0];
    *(uint4*)(Bl + t * 32 + 24) = pk2[1];
  }
  __syncthreads();

  const int lane = t & 63;
  const int wv = t >> 6;
  const int g = wv & 1;    // cout tile: g*32
  const int nh = wv >> 1;  // n-tiles nh*4 .. nh*4+3
  const int ln = lane & 31;
  const int half = lane >> 5;

  const short8 af0 = *(const short8*)(wA + (size_t)(((e * 4 + half) * 64) + g * 32 + ln) * 8);
  const short8 af1 = *(const short8*)(wA + (size_t)(((e * 4 + 2 + half) * 64) + g * 32 + ln) * 8);

  f32x16 acc[4];
#pragma unroll
  for (int tt = 0; tt < 4; tt++)
#pragma unroll
    for (int i = 0; i < 16; i++) acc[tt][i] = 0.f;

#pragma unroll
  for (int tt = 0; tt < 4; tt++) {
    const ushort* bcol = Bl + (size_t)((nh * 4 + tt) * 32 + ln) * 32;
    const short8 b0 = *(const short8*)(bcol + half * 8);
    const short8 b1v = *(const short8*)(bcol + 16 + half * 8);
    acc[tt] = __builtin_amdgcn_mfma_f32_32x32x16_bf16(af0, b0, acc[tt], 0, 0, 0);
    acc[tt] = __builtin_amdgcn_mfma_f32_32x32x16_bf16(af1, b1v, acc[tt], 0, 0, 0);
  }

  float bias[16];
#pragma unroll
  for (int r = 0; r < 16; r++)
    bias[r] = b1e[g * 32 + (r & 3) + 8 * (r >> 2) + 4 * half];

  const int pc = ln >> 1;
#pragma unroll
  for (int j = 0; j < 2; j++) {
    float pw[16];
#pragma unroll
    for (int r = 0; r < 16; r++) {
      float v = fmaxf(acc[2 * j][r], acc[2 * j + 1][r]);
      v = fmaxf(v, __shfl_xor(v, 1));
      pw[r] = fmaxf(v + bias[r], 0.f);
    }
    if ((lane & 1) == 0) {
      const int pos = (4 * q + nh * 2 + j) * 16 + pc;
      ushort* dst = h1q + (size_t)b * 16384 + pos * 8 + 4 * half;
#pragma unroll
      for (int rg = 0; rg < 4; rg++) {
        uint2 pk;
        pk.x = (uint)f2bf(pw[rg * 4 + 0]) | ((uint)f2bf(pw[rg * 4 + 1]) << 16);
        pk.y = (uint)f2bf(pw[rg * 4 + 2]) | ((uint)f2bf(pw[rg * 4 + 3]) << 16);
        *(uint2*)(dst + (g * 4 + rg) * 2048) = pk;
      }
    }
  }
}

// ---------------- K4b: conv2 bf16 MFMA, grid 4096, pipelined A loads -------
// R15 structure: wave = 64 couts x 32 spatial; per (tap,c4): 2 A + 1 B ds
// -> 2 MFMA. NEW: A regs rotated in place — tap kk+1's loads issue right
// after tap kk's MFMAs consume them (full-tap latency budget, partial vmcnt).
__global__ __launch_bounds__(256, 4) void k_conv2(
    const ushort* __restrict__ h1q, const ushort* __restrict__ wp,
    const float* __restrict__ b2, const int* __restrict__ best_idx,
    ushort* __restrict__ h2q) {
  __shared__ uint4 st[864];   // [row 6][cig 8][col 18] x 16B (8 ci bf16)
  __shared__ float pl[2048];  // [cout 128][pooled 16]
  const int blk = blockIdx.x;
  const int b = blk >> 2;
  const int yq = blk & 3;  // out rows yq*4 .. yq*4+3
  const int t = threadIdx.x;
  const int e = __builtin_amdgcn_readfirstlane(best_idx[b]);

  // stage h1 rows yq*4-1 .. yq*4+4 (zero-padded) into LDS
  for (int c = t; c < 864; c += 256) {
    const int row = c / 144;           // 8*18
    const int rem = c - row * 144;
    const int cig = rem / 18;
    const int col = rem - cig * 18;
    const int gy = yq * 4 - 1 + row;
    uint4 v = make_uint4(0u, 0u, 0u, 0u);
    if (gy >= 0 && gy < 16 && col >= 1 && col <= 16)
      v = *(const uint4*)(h1q + (size_t)b * 16384 + cig * 2048 +
                          (gy * 16 + col - 1) * 8);
    st[c] = v;  // c == (row*8+cig)*18+col
  }
  __syncthreads();

  const int wv = t >> 6;
  const int g = wv & 1;       // cout group: g*64
  const int h = wv >> 1;      // strip half: pre-pool rows 2h, 2h+1
  const int lane = t & 63;
  const int n = lane & 31;
  const int half = lane >> 5; // k-half
  const int drow = n >> 4;
  const int col = n & 15;
  const int cm0 = g * 64;

  f32x16 acc0, acc1;
#pragma unroll
  for (int i = 0; i < 16; i++) { acc0[i] = 0.f; acc1[i] = 0.f; }

  // A address: wpe + kk*8192 + ((c4*2+half)*128 + cm0 + {n, 32+n})*8
  //          = abase + kk*8192 + c4*2048 (+256 for the +32-cout fragment)
  const ushort* abase = wp + (size_t)e * 73728 +
                        (size_t)(half * 128 + cm0 + n) * 8;
  const short* sb = (const short*)st;

  // preload tap 0
  short8 a0[4], a1[4];
#pragma unroll
  for (int c4 = 0; c4 < 4; c4++) {
    a0[c4] = *(const short8*)(abase + c4 * 2048);
    a1[c4] = *(const short8*)(abase + c4 * 2048 + 256);
  }

#pragma unroll
  for (int kk = 0; kk < 9; kk++) {
    const int ky = kk / 3;
    const int kx = kk - ky * 3;
#pragma unroll
    for (int c4 = 0; c4 < 4; c4++) {
      const int cig = c4 * 2 + half;
      const short8 bf = *(const short8*)(sb +
          (((2 * h + drow + ky) * 8 + cig) * 18 + col + kx) * 8);
      acc0 = __builtin_amdgcn_mfma_f32_32x32x16_bf16(a0[c4], bf, acc0, 0, 0, 0);
      acc1 = __builtin_amdgcn_mfma_f32_32x32x16_bf16(a1[c4], bf, acc1, 0, 0, 0);
      if (kk < 8) {  // in-place rotate: overwrite just-consumed regs
        a0[c4] = *(const short8*)(abase + (kk + 1) * 8192 + c4 * 2048);
        a1[c4] = *(const short8*)(abase + (kk + 1) * 8192 + c4 * 2048 + 256);
      }
    }
  }

  // fused 2x2 maxpool: cols via shfl_xor(1), rows via shfl_xor(16)
#pragma unroll
  for (int s = 0; s < 2; s++) {
    const f32x16 a = s ? acc1 : acc0;
#pragma unroll
    for (int r = 0; r < 16; r++) {
      float v = a[r];
      v = fmaxf(v, __shfl_xor(v, 1));
      v = fmaxf(v, __shfl_xor(v, 16));
      if ((lane & 17) == 0) {  // col even, drow==0
        const int rowm = (r & 3) + 8 * (r >> 2) + 4 * half;
        const int pc = (n >> 1) & 7;  // pooled col 0..7
        pl[(cm0 + s * 32 + rowm) * 16 + h * 8 + pc] = v;
      }
    }
  }
  __syncthreads();

  // bias + relu + bf16 pack + coalesced write: h2[b][cout][yq*16 + p]
  {
    const int coutL = t >> 1;
    const int hh = t & 1;
    const float bias = b2[e * 128 + coutL];
    const float* src = pl + coutL * 16 + hh * 8;
    union { ushort us[8]; uint4 u4; } pk;
#pragma unroll
    for (int j = 0; j < 8; j++) pk.us[j] = f2bf(fmaxf(src[j] + bias, 0.f));
    *(uint4*)(h2q + (size_t)b * 8192 + coutL * 64 + yq * 16 + hh * 8) = pk.u4;
  }
}

// ---------------- K5: FC bf16 MFMA, split-K=16, partial stores (no atomics) -
__global__ __launch_bounds__(256) void k_fc(
    const ushort* __restrict__ h2q, const ushort* __restrict__ wfc,
    const int* __restrict__ order, const int* __restrict__ off,
    const int* __restrict__ counts, float* __restrict__ partial) {
  __shared__ ushort bs[32 * 32 * 8];  // 16 KB
  __shared__ int sid[32];
  const int tix = blockIdx.x;
  const int ks = blockIdx.y;  // K-slice of 512
  const int base = tix * 32;
  if (base >= off[4]) return;
  int e = 0;
#pragma unroll
  for (int i = 1; i < 4; i++) if (base >= off[i]) e = i;
  const int vend = off[e] + counts[e];
  const int t = threadIdx.x;
  if (t < 32) {
    const int pos = base + t;
    sid[t] = (pos < vend) ? order[pos] : -1;
  }
  __syncthreads();

  const int lane = t & 63;
  const int wv = t >> 6;
  const int half = lane >> 5;
  const int mn = lane & 31;
  const int cout0 = wv * 32;
  const int ss = t & 31;
  const int kgrp = t >> 5;
  const int srow = sid[ss] >= 0 ? sid[ss] : 0;
  const ushort* arow = h2q + (size_t)srow * 8192;

  f32x16 acc;
#pragma unroll
  for (int i = 0; i < 16; i++) acc[i] = 0.f;

  const ushort* wbase = wfc + ((size_t)e * 1024 + (size_t)ks * 64) * 1024;
  const short* sb = (const short*)bs;

#pragma unroll
  for (int ch = 0; ch < 2; ch++) {
    const int k0g = ks * 512 + ch * 256;
    if (ch) __syncthreads();
#pragma unroll
    for (int p = 0; p < 4; p++) {
      const int kb = p * 8 + kgrp;
      const uint4 v = *(const uint4*)(arow + k0g + kb * 8);
      *(uint4*)(bs + (kb * 32 + ss) * 8) = v;
    }
    __syncthreads();
#pragma unroll
    for (int kk = 0; kk < 16; kk++) {
      const int kbl = kk * 2 + half;
      const short8 af = *(const short8*)(wbase +
          ((size_t)(ch * 32 + kbl) * 128 + cout0 + mn) * 8);
      const short8 bf = *(const short8*)(sb + (kbl * 32 + mn) * 8);
      acc = __builtin_amdgcn_mfma_f32_32x32x16_bf16(af, bf, acc, 0, 0, 0);
    }
  }

  float* pks = partial + (size_t)ks * 147456;  // 128*1152
#pragma unroll
  for (int r = 0; r < 16; r++) {
    const int cout = cout0 + (r & 3) + 8 * (r >> 2) + 4 * half;
    pks[(size_t)cout * 1152 + base + mn] = acc[r];
  }
}

// ---------------- K5b: reduce 16 K-slices, +bias, *best_w, write out ------
__global__ __launch_bounds__(256) void k_red(
    const float* __restrict__ partial, const float* __restrict__ efb,
    const int* __restrict__ order, const int* __restrict__ off,
    const int* __restrict__ counts, const float* __restrict__ best_w,
    float* __restrict__ out) {
  const int slot = blockIdx.x * 256 + threadIdx.x;
  if (slot >= off[4]) return;
  int e = 0;
#pragma unroll
  for (int i = 1; i < 4; i++) if (slot >= off[i]) e = i;
  if (slot - off[e] >= counts[e]) return;
  const int s = order[slot];
  const float bw = best_w[s];
  const int o0 = blockIdx.y * 4;
#pragma unroll
  for (int j = 0; j < 4; j++) {
    const int o = o0 + j;
    float sum = 0.f;
#pragma unroll
    for (int ks = 0; ks < 16; ks++)
      sum += partial[(size_t)ks * 147456 + (size_t)o * 1152 + slot];
    out[(size_t)s * 100 + o] = (sum + efb[e * 100 + o]) * bw;
  }
}

// ---------------------------------------------------------------------------
extern "C" void kernel_launch(void* const* d_in, const int* in_sizes, int n_in,
                              void* d_out, int out_size, void* d_ws, size_t ws_size,
                              hipStream_t stream) {
  const float* x   = (const float*)d_in[0];
  const float* gcw = (const float*)d_in[1];
  const float* gcb = (const float*)d_in[2];
  const float* gfw = (const float*)d_in[3];
  const float* gfb = (const float*)d_in[4];
  const float* c1w = (const float*)d_in[5];
  const float* c1b = (const float*)d_in[6];
  const float* c2w = (const float*)d_in[7];
  const float* c2b = (const float*)d_in[8];
  const float* efw = (const float*)d_in[9];
  const float* efb = (const float*)d_in[10];
  float* out = (float*)d_out;
  float* ws  = (float*)d_ws;

  // ws layout (float-element offsets)
  float*  g_mean   = ws;                        // 16384
  float*  best_w   = ws + 16384;                // 1024
  int*    best_idx = (int*)(ws + 17408);        // 1024
  int*    counts   = (int*)(ws + 18432);        // 4
  int*    cnt2     = (int*)(ws + 18436);        // 4
  int*    off      = (int*)(ws + 18440);        // 5
  int*    order    = (int*)(ws + 18448);        // 1152
  ushort* wp       = (ushort*)(ws + 20480);     // 294912 us  = 147456 f
  ushort* wfc      = (ushort*)(ws + 167936);    // 4194304 us = 2097152 f
  ushort* h1       = (ushort*)(ws + 2265088);   // 16777216 us = 8388608 f
  ushort* h2q      = (ushort*)(ws + 10653696);  // 8388608 us = 4194304 f -> ends 14848000
  float*  partial  = ws + 14848000;             // 2359296 f -> ends 17207296
  ushort* wA       = (ushort*)(ws + 17207296);  // 32768 us = 16384 f -> ends 17223680

  float* probs = out + 102400;
  float* aux   = out + 106496;

  hipMemsetAsync(counts, 0, 8 * sizeof(int), stream);  // counts + cnt2

  k_wprep<<<1152, 256, 0, stream>>>(c2w, wp);
  k_w1prep<<<128, 256, 0, stream>>>(c1w, wA);
  k_wfc<<<16384, 256, 0, stream>>>(efw, wfc);
  k_gate<<<1024, 256, 0, stream>>>(x, gcw, gcb, g_mean);
  k_router<<<4, 256, 0, stream>>>(g_mean, gfw, gfb, probs, best_w, best_idx, counts);
  k_offsets<<<1, 64, 0, stream>>>(counts, off);
  k_scatter<<<4, 256, 0, stream>>>(best_idx, off, cnt2, order);
  k_aux<<<1, 256, 0, stream>>>(probs, aux);
  k_conv1<<<4096, 256, 0, stream>>>(x, wA, c1b, best_idx, h1);
  k_conv2<<<4096, 256, 0, stream>>>(h1, wp, c2b, best_idx, h2q);
  dim3 g5(36, 16);
  k_fc<<<g5, 256, 0, stream>>>(h2q, wfc, order, off, counts, partial);
  dim3 g6(5, 25);
  k_red<<<g6, 256, 0, stream>>>(partial, efb, order, off, counts, best_w, out);
}

// Round 19
// 230.418 us; speedup vs baseline: 1.3766x; 1.0792x over previous
//
#include <hip/hip_runtime.h>
#include <hip/hip_bf16.h>
#include <cstdint>

// ---------------------------------------------------------------------------
// MoE CNN, hard top-1 dispatch. Round 19:
//  - conv2 = R17 grid-2048 structure (halved A L2-traffic) + R18's in-place
//    pipelined A loads (latency hiding) — the two verified transforms composed.
//  - router/offsets/scatter/aux fused into one single-block kernel k_route
//    (launches 13 -> 10, memsets dropped).
// Sizes: B=1024, Cin=3, HW=32, GC=16, E=4, C1=64, C2=128, FC_IN=8192, NC=100
// Output: [final 1024*100][probs 1024*4][aux 1]
// ---------------------------------------------------------------------------

#define B_TOT 1024

typedef __attribute__((ext_vector_type(8))) short short8;
typedef __attribute__((ext_vector_type(16))) float f32x16;

__device__ __forceinline__ ushort f2bf(float f) {
  uint32_t u = __float_as_uint(f);
  u += 0x7fffu + ((u >> 16) & 1u);  // round-to-nearest-even
  return (ushort)(u >> 16);
}

// ------- K0: w2 fp32 [e][cout][ci][3][3] -> bf16 [e][kk][kb 8][cout 128][8] -
__global__ __launch_bounds__(256) void k_wprep(const float* __restrict__ w2,
                                               ushort* __restrict__ wp) {
  const int i = blockIdx.x * 256 + threadIdx.x;  // 294912 total
  const int j = i & 7;
  const int cout = (i >> 3) & 127;
  const int kb = (i >> 10) & 7;
  const int kkE = i >> 13;          // e*9 + kk
  const int kk = kkE - (kkE / 9) * 9;
  const int e = kkE / 9;
  const int ci = kb * 8 + j;
  const float f = w2[(size_t)(((e * 128 + cout) * 64 + ci) * 9) + kk];
  wp[i] = f2bf(f);
}

// ------- K0c: w1 fp32 [e][64][3][3][3] -> bf16 wA [e][kb 4][cout 64][8] ----
__global__ __launch_bounds__(256) void k_w1prep(const float* __restrict__ w1,
                                                ushort* __restrict__ wA) {
  const int i = blockIdx.x * 256 + threadIdx.x;  // 32768 total
  const int j = i & 7;
  const int cout = (i >> 3) & 63;
  const int kb = (i >> 9) & 3;
  const int e = i >> 11;
  const int k = kb * 8 + j;
  float f = 0.f;
  if (k < 27) {
    const int ci = k / 9;
    const int kk = k - ci * 9;
    f = w1[(size_t)(((e * 64 + cout) * 3 + ci) * 9) + kk];
  }
  wA[i] = f2bf(f);
}

// ---------------- K0b: efw fp32 [e][100][8192] -> bf16 [e][kb][cout128][8] -
__global__ __launch_bounds__(256) void k_wfc(const float* __restrict__ efw,
                                             ushort* __restrict__ wfc) {
  const int i = blockIdx.x * 256 + threadIdx.x;  // 4194304 total
  const int j = i & 7;
  const int cout = (i >> 3) & 127;
  const int kb = (i >> 10) & 1023;
  const int e = i >> 20;
  const int k = kb * 8 + j;
  float f = 0.f;
  if (cout < 100) f = efw[((size_t)(e * 100 + cout)) * 8192 + k];
  wfc[i] = f2bf(f);
}

// ---------------- K1: gate conv(3->16)+relu+gap, LDS halo, maskless --------
__global__ __launch_bounds__(256, 2) void k_gate(
    const float* __restrict__ x, const float* __restrict__ gcw,
    const float* __restrict__ gcb, float* __restrict__ g_mean) {
  __shared__ float xs[3 * 34 * 34];  // 13872 B zero-padded halo
  __shared__ float red[4 * 16];
  const int b = blockIdx.x;
  const int t = threadIdx.x;
  const float* xb = x + (size_t)b * 3072;

  for (int c = t; c < 3468; c += 256) {
    const int ci = c / 1156;
    const int rem = c - ci * 1156;
    const int y = rem / 34;
    const int xx = rem - y * 34;
    const int gy = y - 1, gx = xx - 1;
    float v = 0.f;
    if (gy >= 0 && gy < 32 && gx >= 0 && gx < 32) v = xb[ci * 1024 + gy * 32 + gx];
    xs[c] = v;
  }
  __syncthreads();

  const int r = t >> 3;        // output row 0..31
  const int c0 = (t & 7) * 4;  // output col base

  float accp[16][4];
#pragma unroll
  for (int c = 0; c < 16; c++)
#pragma unroll
    for (int p = 0; p < 4; p++) accp[c][p] = 0.f;

#pragma unroll
  for (int ci = 0; ci < 3; ci++) {
    float pv[3][6];
#pragma unroll
    for (int dy = 0; dy < 3; dy++) {
      const float* row = xs + ci * 1156 + (r + dy) * 34 + c0;
#pragma unroll
      for (int dx = 0; dx < 6; dx++) pv[dy][dx] = row[dx];
    }
#pragma unroll
    for (int c = 0; c < 16; c++) {
      const float* wr = gcw + (c * 3 + ci) * 9;
#pragma unroll
      for (int ky = 0; ky < 3; ky++)
#pragma unroll
        for (int kx = 0; kx < 3; kx++) {
          const float wv = wr[ky * 3 + kx];
#pragma unroll
          for (int p = 0; p < 4; p++)
            accp[c][p] += wv * pv[ky][kx + p];
        }
    }
  }

  float sums[16];
#pragma unroll
  for (int c = 0; c < 16; c++) {
    const float bb = gcb[c];
    float s = 0.f;
#pragma unroll
    for (int p = 0; p < 4; p++) s += fmaxf(accp[c][p] + bb, 0.f);
    sums[c] = s;
  }

  const int wave = t >> 6, lane = t & 63;
#pragma unroll
  for (int c = 0; c < 16; c++) {
    float v = sums[c];
    for (int o = 32; o > 0; o >>= 1) v += __shfl_down(v, o);
    if (lane == 0) red[wave * 16 + c] = v;
  }
  __syncthreads();
  if (t < 16) {
    g_mean[b * 16 + t] =
        (red[t] + red[16 + t] + red[32 + t] + red[48 + t]) * (1.f / 1024.f);
  }
}

// ---------------- K2: fused router+softmax+argmax+offsets+scatter+aux ------
// Single block, 256 threads — no cross-block ordering assumptions.
__global__ __launch_bounds__(256) void k_route(
    const float* __restrict__ g_mean, const float* __restrict__ gfw,
    const float* __restrict__ gfb, float* __restrict__ probs,
    float* __restrict__ best_w, int* __restrict__ best_idx,
    int* __restrict__ off_g, int* __restrict__ counts_g,
    int* __restrict__ order, float* __restrict__ aux_out) {
  __shared__ int cnt[4], ofs[5], cl[4];
  __shared__ short bidx[1024];
  __shared__ float red[16];
  const int t = threadIdx.x;
  if (t < 4) { cnt[t] = 0; cl[t] = 0; }
  __syncthreads();

  float asum[4] = {0.f, 0.f, 0.f, 0.f};
  for (int s = t; s < B_TOT; s += 256) {
    float g[16];
#pragma unroll
    for (int c = 0; c < 16; c++) g[c] = g_mean[s * 16 + c];
    float lg[4];
#pragma unroll
    for (int e = 0; e < 4; e++) {
      float sum = gfb[e];
#pragma unroll
      for (int c = 0; c < 16; c++) sum += g[c] * gfw[e * 16 + c];
      lg[e] = sum;
    }
    const float m = fmaxf(fmaxf(lg[0], lg[1]), fmaxf(lg[2], lg[3]));
    float ex[4], ssum = 0.f;
#pragma unroll
    for (int e = 0; e < 4; e++) { ex[e] = expf(lg[e] - m); ssum += ex[e]; }
    const float inv = 1.f / ssum;
    float p[4];
#pragma unroll
    for (int e = 0; e < 4; e++) {
      p[e] = ex[e] * inv;
      probs[s * 4 + e] = p[e];
      asum[e] += p[e];
    }
    int bi = 0; float bp = p[0];
#pragma unroll
    for (int e = 1; e < 4; e++) if (p[e] > bp) { bp = p[e]; bi = e; }
    best_w[s] = bp;
    best_idx[s] = bi;
    bidx[s] = (short)bi;
    atomicAdd(&cnt[bi], 1);
  }
  __syncthreads();

  if (t == 0) {
    int o = 0;
#pragma unroll
    for (int e = 0; e < 4; e++) { ofs[e] = o; o += ((cnt[e] + 31) & ~31); }
    ofs[4] = o;
#pragma unroll
    for (int i = 0; i < 5; i++) off_g[i] = ofs[i];
#pragma unroll
    for (int e = 0; e < 4; e++) counts_g[e] = cnt[e];
  }
  __syncthreads();

  for (int s = t; s < B_TOT; s += 256) {
    const int e2 = bidx[s];
    const int slot = ofs[e2] + atomicAdd(&cl[e2], 1);
    order[slot] = s;
  }

  // aux loss
  const int wave = t >> 6, lane = t & 63;
#pragma unroll
  for (int e = 0; e < 4; e++) {
    float v = asum[e];
    for (int o = 32; o > 0; o >>= 1) v += __shfl_down(v, o);
    if (lane == 0) red[wave * 4 + e] = v;
  }
  __syncthreads();
  if (t == 0) {
    float aux = 0.f;
#pragma unroll
    for (int e = 0; e < 4; e++) {
      const float mp = (red[e] + red[4 + e] + red[8 + e] + red[12 + e]) * (1.f / 1024.f);
      const float d = mp - 0.25f;
      aux += d * d;
    }
    aux_out[0] = aux * 0.25f;
  }
}

// ---------------- K4: conv1 via bf16 MFMA implicit GEMM (R15, verified) ----
__global__ __launch_bounds__(256) void k_conv1(
    const float* __restrict__ x, const ushort* __restrict__ wA,
    const float* __restrict__ b1, const int* __restrict__ best_idx,
    ushort* __restrict__ h1q) {
  __shared__ ushort xs[1020];                    // [ci 3][hr 10][hc 34] bf16
  __shared__ __align__(16) ushort Bl[256 * 32];  // [pos][Kpad] 16 KB
  const int blk = blockIdx.x;
  const int b = blk >> 2;
  const int q = blk & 3;  // strip: pre-pool rows 8q..8q+7
  const int t = threadIdx.x;
  const int e = __builtin_amdgcn_readfirstlane(best_idx[b]);
  const float* xb = x + (size_t)b * 3072;
  const float* b1e = b1 + (size_t)e * 64;

  for (int c = t; c < 1020; c += 256) {
    const int ci = c / 340;
    const int rem = c - ci * 340;
    const int hr = rem / 34;
    const int hc = rem - hr * 34;
    const int gr = 8 * q + hr - 1, gc = hc - 1;
    float v = 0.f;
    if (gr >= 0 && gr < 32 && gc >= 0 && gc < 32) v = xb[ci * 1024 + gr * 32 + gc];
    xs[c] = f2bf(v);
  }
  __syncthreads();

  {
    const int rr = t >> 5, cc = t & 31;
    ushort us[32];
#pragma unroll
    for (int k = 0; k < 32; k++) {
      ushort v = 0;
      if (k < 27) {
        const int ci = k / 9;
        const int tap = k - ci * 9;
        const int dy = tap / 3, dx = tap - dy * 3;
        v = xs[ci * 340 + (rr + dy) * 34 + cc + dx];
      }
      us[k] = v;
    }
    uint4 pk[2];
    uint* pu = (uint*)pk;
#pragma unroll
    for (int w = 0; w < 8; w++)
      pu[w] = (uint)us[w * 2] | ((uint)us[w * 2 + 1] << 16);
    *(uint4*)(Bl + t * 32) = pk[0];
    *(uint4*)(Bl + t * 32 + 8) = pk[1];
    uint4 pk2[2];
    uint* pu2 = (uint*)pk2;
#pragma unroll
    for (int w = 0; w < 8; w++)
      pu2[w] = (uint)us[16 + w * 2] | ((uint)us[16 + w * 2 + 1] << 16);
    *(uint4*)(Bl + t * 32 + 16) = pk2[0];
    *(uint4*)(Bl + t * 32 + 24) = pk2[1];
  }
  __syncthreads();

  const int lane = t & 63;
  const int wv = t >> 6;
  const int g = wv & 1;    // cout tile: g*32
  const int nh = wv >> 1;  // n-tiles nh*4 .. nh*4+3
  const int ln = lane & 31;
  const int half = lane >> 5;

  const short8 af0 = *(const short8*)(wA + (size_t)(((e * 4 + half) * 64) + g * 32 + ln) * 8);
  const short8 af1 = *(const short8*)(wA + (size_t)(((e * 4 + 2 + half) * 64) + g * 32 + ln) * 8);

  f32x16 acc[4];
#pragma unroll
  for (int tt = 0; tt < 4; tt++)
#pragma unroll
    for (int i = 0; i < 16; i++) acc[tt][i] = 0.f;

#pragma unroll
  for (int tt = 0; tt < 4; tt++) {
    const ushort* bcol = Bl + (size_t)((nh * 4 + tt) * 32 + ln) * 32;
    const short8 b0 = *(const short8*)(bcol + half * 8);
    const short8 b1v = *(const short8*)(bcol + 16 + half * 8);
    acc[tt] = __builtin_amdgcn_mfma_f32_32x32x16_bf16(af0, b0, acc[tt], 0, 0, 0);
    acc[tt] = __builtin_amdgcn_mfma_f32_32x32x16_bf16(af1, b1v, acc[tt], 0, 0, 0);
  }

  float bias[16];
#pragma unroll
  for (int r = 0; r < 16; r++)
    bias[r] = b1e[g * 32 + (r & 3) + 8 * (r >> 2) + 4 * half];

  const int pc = ln >> 1;
#pragma unroll
  for (int j = 0; j < 2; j++) {
    float pw[16];
#pragma unroll
    for (int r = 0; r < 16; r++) {
      float v = fmaxf(acc[2 * j][r], acc[2 * j + 1][r]);
      v = fmaxf(v, __shfl_xor(v, 1));
      pw[r] = fmaxf(v + bias[r], 0.f);
    }
    if ((lane & 1) == 0) {
      const int pos = (4 * q + nh * 2 + j) * 16 + pc;
      ushort* dst = h1q + (size_t)b * 16384 + pos * 8 + 4 * half;
#pragma unroll
      for (int rg = 0; rg < 4; rg++) {
        uint2 pk;
        pk.x = (uint)f2bf(pw[rg * 4 + 0]) | ((uint)f2bf(pw[rg * 4 + 1]) << 16);
        pk.y = (uint)f2bf(pw[rg * 4 + 2]) | ((uint)f2bf(pw[rg * 4 + 3]) << 16);
        *(uint2*)(dst + (g * 4 + rg) * 2048) = pk;
      }
    }
  }
}

// ---------------- K4b: conv2 bf16 MFMA, grid 2048 + pipelined A loads ------
// R17 structure (halved A L2-traffic, 23 KB LDS) + R18 in-place A rotation.
// Wave wv: cout group g=wv&1 (64), row-quad h=wv>>1. Per (tap,c4):
// 2 A (prefetched) + 2 B ds_reads -> 4 MFMA.
__global__ __launch_bounds__(256, 2) void k_conv2(
    const ushort* __restrict__ h1q, const ushort* __restrict__ wp,
    const float* __restrict__ b2, const int* __restrict__ best_idx,
    ushort* __restrict__ h2q) {
  __shared__ uint4 st[1440];  // [row 10][cig 8][col 18] x 16B
  const int blk = blockIdx.x;
  const int b = blk >> 1;
  const int q = blk & 1;  // out rows 8q..8q+7
  const int t = threadIdx.x;
  const int e = __builtin_amdgcn_readfirstlane(best_idx[b]);
  const ushort* wpe = wp + (size_t)e * 73728;

  // stage halo rows 8q-1 .. 8q+8 (zero-padded)  [R17-verified]
  for (int c = t; c < 1440; c += 256) {
    const int row = c / 144;
    const int rem = c - row * 144;
    const int cig = rem / 18;
    const int col = rem - cig * 18;
    const int gy = 8 * q - 1 + row, gx = col - 1;
    uint4 v = make_uint4(0u, 0u, 0u, 0u);
    if (gy >= 0 && gy < 16 && gx >= 0 && gx < 16)
      v = *(const uint4*)(h1q + (size_t)b * 16384 + cig * 2048 + (gy * 16 + gx) * 8);
    st[c] = v;  // index (row*8+cig)*18+col
  }
  __syncthreads();

  const int lane = t & 63;
  const int wv = t >> 6;
  const int g = wv & 1;       // cout half: base g*64
  const int h = wv >> 1;      // strip row-quad: local rows 4h..4h+3
  const int half = lane >> 5; // k-half
  const int n = lane & 31;
  const int drow = n >> 4;
  const int col15 = n & 15;
  const int cm0 = g * 64;

  f32x16 acc[2][2];  // [m: cout tile][nt: row pair]
#pragma unroll
  for (int m = 0; m < 2; m++)
#pragma unroll
    for (int nt = 0; nt < 2; nt++)
#pragma unroll
      for (int i = 0; i < 16; i++) acc[m][nt][i] = 0.f;

  const short* sbs = (const short*)st;
  // A addr: wpe + kk*8192 + ((c4*2+half)*128 + cm0 + {n, 32+n})*8
  //       = abase + kk*8192 + c4*2048 (+256 for +32 couts)
  const ushort* abase = wpe + (size_t)(half * 128 + cm0 + n) * 8;

  short8 a0[4], a1[4];  // prefetch tap 0
#pragma unroll
  for (int c4 = 0; c4 < 4; c4++) {
    a0[c4] = *(const short8*)(abase + c4 * 2048);
    a1[c4] = *(const short8*)(abase + c4 * 2048 + 256);
  }

#pragma unroll
  for (int kk = 0; kk < 9; kk++) {
    const int ky = kk / 3;
    const int kx = kk - ky * 3;
#pragma unroll
    for (int c4 = 0; c4 < 4; c4++) {
      const int kb = c4 * 2 + half;
#pragma unroll
      for (int nt = 0; nt < 2; nt++) {
        const int rin = 4 * h + 2 * nt + drow + ky;  // halo row 0..9
        const int cin = col15 + kx;                  // halo col 0..17
        const short8 bf = *(const short8*)(sbs + ((rin * 8 + kb) * 18 + cin) * 8);
        acc[0][nt] = __builtin_amdgcn_mfma_f32_32x32x16_bf16(a0[c4], bf, acc[0][nt], 0, 0, 0);
        acc[1][nt] = __builtin_amdgcn_mfma_f32_32x32x16_bf16(a1[c4], bf, acc[1][nt], 0, 0, 0);
      }
      if (kk < 8) {  // in-place rotate: overwrite just-consumed regs
        a0[c4] = *(const short8*)(abase + (kk + 1) * 8192 + c4 * 2048);
        a1[c4] = *(const short8*)(abase + (kk + 1) * 8192 + c4 * 2048 + 256);
      }
    }
  }
  __syncthreads();  // done reading halo before LDS reuse

  // epilogue [R17-verified]: fused 2x2 maxpool + bias + relu + bf16
  // pls layout: [cout 128][prl 4][pc 8]  (prl = 2h+nt, abs pooled row 4q+prl)
  ushort* pls = (ushort*)st;
#pragma unroll
  for (int m = 0; m < 2; m++)
#pragma unroll
    for (int nt = 0; nt < 2; nt++) {
#pragma unroll
      for (int r = 0; r < 16; r++) {
        float v = acc[m][nt][r];
        v = fmaxf(v, __shfl_xor(v, 1));
        v = fmaxf(v, __shfl_xor(v, 16));
        if ((lane & 17) == 0) {  // col even, drow==0
          const int rowm = (r & 3) + 8 * (r >> 2) + 4 * half;
          const int cout = cm0 + m * 32 + rowm;
          const int prl = 2 * h + nt;
          const int pc = (n >> 1) & 7;
          pls[cout * 32 + prl * 8 + pc] = f2bf(fmaxf(v + b2[e * 128 + cout], 0.f));
        }
      }
    }
  __syncthreads();

  // coalesced copy: 512 uint4; dst = h2q[b][cout][4q+prl][pc]
  {
#pragma unroll
    for (int p = 0; p < 2; p++) {
      const int f16 = p * 256 + t;      // uint4 index
      const int flat = f16 * 8;         // ushort index: cout*32 + pos32
      const int cout = flat >> 5;
      const int pos32 = flat & 31;
      uint4* dst = (uint4*)(h2q + (size_t)b * 8192 + cout * 64 + 32 * q + pos32);
      *dst = ((const uint4*)pls)[f16];
    }
  }
}

// ---------------- K5: FC bf16 MFMA, split-K=16, partial stores (no atomics) -
__global__ __launch_bounds__(256) void k_fc(
    const ushort* __restrict__ h2q, const ushort* __restrict__ wfc,
    const int* __restrict__ order, const int* __restrict__ off,
    const int* __restrict__ counts, float* __restrict__ partial) {
  __shared__ ushort bs[32 * 32 * 8];  // 16 KB
  __shared__ int sid[32];
  const int tix = blockIdx.x;
  const int ks = blockIdx.y;  // K-slice of 512
  const int base = tix * 32;
  if (base >= off[4]) return;
  int e = 0;
#pragma unroll
  for (int i = 1; i < 4; i++) if (base >= off[i]) e = i;
  const int vend = off[e] + counts[e];
  const int t = threadIdx.x;
  if (t < 32) {
    const int pos = base + t;
    sid[t] = (pos < vend) ? order[pos] : -1;
  }
  __syncthreads();

  const int lane = t & 63;
  const int wv = t >> 6;
  const int half = lane >> 5;
  const int mn = lane & 31;
  const int cout0 = wv * 32;
  const int ss = t & 31;
  const int kgrp = t >> 5;
  const int srow = sid[ss] >= 0 ? sid[ss] : 0;
  const ushort* arow = h2q + (size_t)srow * 8192;

  f32x16 acc;
#pragma unroll
  for (int i = 0; i < 16; i++) acc[i] = 0.f;

  const ushort* wbase = wfc + ((size_t)e * 1024 + (size_t)ks * 64) * 1024;
  const short* sb = (const short*)bs;

#pragma unroll
  for (int ch = 0; ch < 2; ch++) {
    const int k0g = ks * 512 + ch * 256;
    if (ch) __syncthreads();
#pragma unroll
    for (int p = 0; p < 4; p++) {
      const int kb = p * 8 + kgrp;
      const uint4 v = *(const uint4*)(arow + k0g + kb * 8);
      *(uint4*)(bs + (kb * 32 + ss) * 8) = v;
    }
    __syncthreads();
#pragma unroll
    for (int kk = 0; kk < 16; kk++) {
      const int kbl = kk * 2 + half;
      const short8 af = *(const short8*)(wbase +
          ((size_t)(ch * 32 + kbl) * 128 + cout0 + mn) * 8);
      const short8 bf = *(const short8*)(sb + (kbl * 32 + mn) * 8);
      acc = __builtin_amdgcn_mfma_f32_32x32x16_bf16(af, bf, acc, 0, 0, 0);
    }
  }

  float* pks = partial + (size_t)ks * 147456;  // 128*1152
#pragma unroll
  for (int r = 0; r < 16; r++) {
    const int cout = cout0 + (r & 3) + 8 * (r >> 2) + 4 * half;
    pks[(size_t)cout * 1152 + base + mn] = acc[r];
  }
}

// ---------------- K5b: reduce 16 K-slices, +bias, *best_w, write out ------
__global__ __launch_bounds__(256) void k_red(
    const float* __restrict__ partial, const float* __restrict__ efb,
    const int* __restrict__ order, const int* __restrict__ off,
    const int* __restrict__ counts, const float* __restrict__ best_w,
    float* __restrict__ out) {
  const int slot = blockIdx.x * 256 + threadIdx.x;
  if (slot >= off[4]) return;
  int e = 0;
#pragma unroll
  for (int i = 1; i < 4; i++) if (slot >= off[i]) e = i;
  if (slot - off[e] >= counts[e]) return;
  const int s = order[slot];
  const float bw = best_w[s];
  const int o0 = blockIdx.y * 4;
#pragma unroll
  for (int j = 0; j < 4; j++) {
    const int o = o0 + j;
    float sum = 0.f;
#pragma unroll
    for (int ks = 0; ks < 16; ks++)
      sum += partial[(size_t)ks * 147456 + (size_t)o * 1152 + slot];
    out[(size_t)s * 100 + o] = (sum + efb[e * 100 + o]) * bw;
  }
}

// ---------------------------------------------------------------------------
extern "C" void kernel_launch(void* const* d_in, const int* in_sizes, int n_in,
                              void* d_out, int out_size, void* d_ws, size_t ws_size,
                              hipStream_t stream) {
  const float* x   = (const float*)d_in[0];
  const float* gcw = (const float*)d_in[1];
  const float* gcb = (const float*)d_in[2];
  const float* gfw = (const float*)d_in[3];
  const float* gfb = (const float*)d_in[4];
  const float* c1w = (const float*)d_in[5];
  const float* c1b = (const float*)d_in[6];
  const float* c2w = (const float*)d_in[7];
  const float* c2b = (const float*)d_in[8];
  const float* efw = (const float*)d_in[9];
  const float* efb = (const float*)d_in[10];
  float* out = (float*)d_out;
  float* ws  = (float*)d_ws;

  // ws layout (float-element offsets)
  float*  g_mean   = ws;                        // 16384
  float*  best_w   = ws + 16384;                // 1024
  int*    best_idx = (int*)(ws + 17408);        // 1024
  int*    counts   = (int*)(ws + 18432);        // 4
  int*    off      = (int*)(ws + 18440);        // 5
  int*    order    = (int*)(ws + 18448);        // 1152
  ushort* wp       = (ushort*)(ws + 20480);     // 294912 us  = 147456 f
  ushort* wfc      = (ushort*)(ws + 167936);    // 4194304 us = 2097152 f
  ushort* h1       = (ushort*)(ws + 2265088);   // 16777216 us = 8388608 f
  ushort* h2q      = (ushort*)(ws + 10653696);  // 8388608 us = 4194304 f -> ends 14848000
  float*  partial  = ws + 14848000;             // 2359296 f -> ends 17207296
  ushort* wA       = (ushort*)(ws + 17207296);  // 32768 us = 16384 f -> ends 17223680

  float* probs = out + 102400;
  float* aux   = out + 106496;

  k_wprep<<<1152, 256, 0, stream>>>(c2w, wp);
  k_w1prep<<<128, 256, 0, stream>>>(c1w, wA);
  k_wfc<<<16384, 256, 0, stream>>>(efw, wfc);
  k_gate<<<1024, 256, 0, stream>>>(x, gcw, gcb, g_mean);
  k_route<<<1, 256, 0, stream>>>(g_mean, gfw, gfb, probs, best_w, best_idx,
                                 off, counts, order, aux);
  k_conv1<<<4096, 256, 0, stream>>>(x, wA, c1b, best_idx, h1);
  k_conv2<<<2048, 256, 0, stream>>>(h1, wp, c2b, best_idx, h2q);
  dim3 g5(36, 16);
  k_fc<<<g5, 256, 0, stream>>>(h2q, wfc, order, off, counts, partial);
  dim3 g6(5, 25);
  k_red<<<g6, 256, 0, stream>>>(partial, efb, order, off, counts, best_w, out);
}